// Round 11
// baseline (5144.899 us; speedup 1.0000x reference)
//
#include <hip/hip_runtime.h>

typedef unsigned int u32;
typedef unsigned long long u64;
typedef float v2f __attribute__((ext_vector_type(2)));

#define BB 4
#define NP0 4096
#define KNB 90
#define CC0 72

// ---------------- fused input conversion ----------------
__global__ void k_init(const float* __restrict__ xyz, const float* __restrict__ x,
                       float* __restrict__ xs, float* __restrict__ ys, float* __restrict__ zs,
                       float* __restrict__ feat){
  int i = blockIdx.x*blockDim.x + threadIdx.x;
  if (i < BB*NP0){
    xs[i] = xyz[3*i+0];
    ys[i] = xyz[3*i+1];
    zs[i] = xyz[3*i+2];
  }
  if (i < BB*NP0*36){
    int j = i % 36; int bn = i / 36;
    int n = bn % NP0, b = bn / NP0;
    int cin = j / 12, f = j % 12;
    float xv = x[(b*3+cin)*NP0 + n];
    float rcp = __powf(1000.0f, -(float)f / 12.0f);
    float a = (100.0f * xv) * rcp;
    float sn, cs; __sincosf(a, &sn, &cs);
    float2 v = make_float2(sn, cs);
    *(float2*)(feat + (size_t)bn*CC0 + cin*24 + 2*f) = v;
  }
}

// Wave64 argmax: DPP fmax chain -> readlane(63) for max; ballot+ffs -> winning
// lane (smallest lane = smallest global index, jnp.argmax tie rule); readlane
// for the index. No ds_bpermute anywhere.
__device__ __forceinline__ void wave_argmax(float bd, int bi, float &smax, int &wbi){
  float v = bd;
  #define DPP_MAX(ctrl) do{ int _t = __builtin_amdgcn_mov_dpp(__float_as_int(v), (ctrl), 0xf, 0xf, true); \
                            v = fmaxf(v, __int_as_float(_t)); }while(0)
  DPP_MAX(0x111); DPP_MAX(0x112); DPP_MAX(0x114); DPP_MAX(0x118); // row_shr 1,2,4,8
  DPP_MAX(0x142); DPP_MAX(0x143);                                 // row_bcast15, row_bcast31
  #undef DPP_MAX
  smax = __int_as_float(__builtin_amdgcn_readlane(__float_as_int(v), 63));
  u64 msk = __ballot(bd == smax);
  int winlane = (int)__ffsll((long long)msk) - 1;
  wbi = __builtin_amdgcn_readlane(bi, winlane);
}

// ---------------- FPS (exact, batch 0) ----------------
// Packed-fp32 distance update (v_pk_mul/add are IEEE rn per lane, association
// (dx^2+dy^2)+dz^2 preserved, contract(off) -> bit-identical to numpy f32).
// Within-thread strict > keeps smallest index on ties (even element first).
// NOTE: no winner-coord tracking in dist loop (R6: VGPR spill).

// 4-wave version (stages 0,1): 256 thr, PPT=N/256. Also zeroes sums[0..3].
template<int PPT>
__global__ __launch_bounds__(256)
void k_fps4(const float* __restrict__ xs, const float* __restrict__ ys, const float* __restrict__ zs,
            int N, int G, int* __restrict__ fi,
            float* __restrict__ nxs, float* __restrict__ nys, float* __restrict__ nzs,
            float* __restrict__ sums){
  constexpr int PH = PPT/2;
  __shared__ float4 sp[4096];
  __shared__ int sfi[2048];
  __shared__ u64 cand[2][4];
  int tid = threadIdx.x;
  const int base = tid * PPT;
  int wv = tid >> 6;
  int lane = tid & 63;
  if (tid < 4) sums[tid] = 0.f;
  v2f px[PH], py[PH], pz[PH], dmn[PH];
  #pragma unroll
  for (int j=0;j<PH;j++){
    int n = base + 2*j;
    float2 ax = *(const float2*)(xs+n);
    float2 ay = *(const float2*)(ys+n);
    float2 az = *(const float2*)(zs+n);
    px[j] = (v2f){ax.x, ax.y};
    py[j] = (v2f){ay.x, ay.y};
    pz[j] = (v2f){az.x, az.y};
    sp[n]   = make_float4(ax.x, ay.x, az.x, 0.f);
    sp[n+1] = make_float4(ax.y, ay.y, az.y, 0.f);
    dmn[j] = (v2f){INFINITY, INFINITY};
  }
  if (tid==0){ sfi[0]=0; }
  float lx = xs[0], ly = ys[0], lz = zs[0];
  __syncthreads();
  for (int t=1; t<G; t++){
    float bd = -INFINITY; int bi = base;
    v2f lx2 = (v2f){lx,lx}, ly2 = (v2f){ly,ly}, lz2 = (v2f){lz,lz};
    {
      #pragma clang fp contract(off)
      #pragma unroll
      for (int j=0;j<PH;j++){
        v2f dx = px[j] - lx2;
        v2f dy = py[j] - ly2;
        v2f dz = pz[j] - lz2;
        v2f d2 = (dx*dx + dy*dy) + dz*dz;
        v2f dmo = dmn[j];
        float dm0 = fminf(dmo.x, d2.x);
        float dm1 = fminf(dmo.y, d2.y);
        dmn[j] = (v2f){dm0, dm1};
        bool g0 = dm0 > bd;
        bd = g0 ? dm0 : bd;
        bi = g0 ? (base + 2*j) : bi;
        bool g1 = dm1 > bd;
        bd = g1 ? dm1 : bd;
        bi = g1 ? (base + 2*j + 1) : bi;
      }
    }
    float smax; int wbi;
    wave_argmax(bd, bi, smax, wbi);
    int par = t & 1;
    if (lane == 0) cand[par][wv] = ((u64)__float_as_uint(smax) << 32) | (u32)(~(u32)wbi);
    __syncthreads();
    u64 k0 = cand[par][0], k1 = cand[par][1], k2 = cand[par][2], k3 = cand[par][3];
    u64 ka = k0 > k1 ? k0 : k1;
    u64 kb = k2 > k3 ? k2 : k3;
    u64 km = ka > kb ? ka : kb;
    int w = (int)(~(u32)km);
    if ((u32)w >= (u32)N) w = 0;
    float4 p = sp[w];
    lx = p.x; ly = p.y; lz = p.z;
    if (tid==0){ sfi[t] = w; }
  }
  __syncthreads();
  for (int i = tid; i < G; i += 256) fi[i] = sfi[i];
  for (int i = tid; i < BB*G; i += 256){
    int b = i / G, g = i % G;
    int idx = sfi[g];
    nxs[i] = xs[(size_t)b*N + idx];
    nys[i] = ys[(size_t)b*N + idx];
    nzs[i] = zs[(size_t)b*N + idx];
  }
}

// single-wave version (stages 2,3): 64 thr, PPT=N/64. NO barriers, NO exchange.
template<int PPT>
__global__ __launch_bounds__(64, 1)
void k_fps1(const float* __restrict__ xs, const float* __restrict__ ys, const float* __restrict__ zs,
            int N, int G, int* __restrict__ fi,
            float* __restrict__ nxs, float* __restrict__ nys, float* __restrict__ nzs,
            float* __restrict__ sums){
  constexpr int PH = PPT/2;
  __shared__ float4 sp[1024];
  __shared__ int sfi[512];
  int tid = threadIdx.x;
  const int base = tid * PPT;
  if (tid < 4) sums[tid] = 0.f;
  v2f px[PH], py[PH], pz[PH], dmn[PH];
  #pragma unroll
  for (int j=0;j<PH;j++){
    int n = base + 2*j;
    float2 ax = *(const float2*)(xs+n);
    float2 ay = *(const float2*)(ys+n);
    float2 az = *(const float2*)(zs+n);
    px[j] = (v2f){ax.x, ax.y};
    py[j] = (v2f){ay.x, ay.y};
    pz[j] = (v2f){az.x, az.y};
    sp[n]   = make_float4(ax.x, ay.x, az.x, 0.f);
    sp[n+1] = make_float4(ax.y, ay.y, az.y, 0.f);
    dmn[j] = (v2f){INFINITY, INFINITY};
  }
  if (tid==0){ sfi[0]=0; }
  float lx = xs[0], ly = ys[0], lz = zs[0];
  __syncthreads();  // one wave: cheap; orders staging writes before dynamic reads
  for (int t=1; t<G; t++){
    float bd = -INFINITY; int bi = base;
    v2f lx2 = (v2f){lx,lx}, ly2 = (v2f){ly,ly}, lz2 = (v2f){lz,lz};
    {
      #pragma clang fp contract(off)
      #pragma unroll
      for (int j=0;j<PH;j++){
        v2f dx = px[j] - lx2;
        v2f dy = py[j] - ly2;
        v2f dz = pz[j] - lz2;
        v2f d2 = (dx*dx + dy*dy) + dz*dz;
        v2f dmo = dmn[j];
        float dm0 = fminf(dmo.x, d2.x);
        float dm1 = fminf(dmo.y, d2.y);
        dmn[j] = (v2f){dm0, dm1};
        bool g0 = dm0 > bd;
        bd = g0 ? dm0 : bd;
        bi = g0 ? (base + 2*j) : bi;
        bool g1 = dm1 > bd;
        bd = g1 ? dm1 : bd;
        bi = g1 ? (base + 2*j + 1) : bi;
      }
    }
    float smax; int w;
    wave_argmax(bd, bi, smax, w);
    if ((u32)w >= (u32)N) w = 0;
    float4 p = sp[w];
    lx = p.x; ly = p.y; lz = p.z;
    if (tid==0){ sfi[t] = w; }
  }
  for (int i = tid; i < G; i += 64) fi[i] = sfi[i];
  for (int i = tid; i < BB*G; i += 64){
    int b = i / G, g = i % G;
    int idx = sfi[g];
    nxs[i] = xs[(size_t)b*N + idx];
    nys[i] = ys[(size_t)b*N + idx];
    nzs[i] = zs[(size_t)b*N + idx];
  }
}

// ---------------- fused kNN (exact radix select) + std partial sums ----------------
__device__ float blockReduceSum(float v, float* sRed){
  for (int off=32; off; off>>=1) v += __shfl_down(v, off, 64);
  int wid = threadIdx.x >> 6, lane = threadIdx.x & 63;
  __syncthreads();
  if (lane==0) sRed[wid] = v;
  __syncthreads();
  float r = 0;
  if (threadIdx.x == 0){ for (int i=0;i<4;i++) r += sRed[i]; }
  return r;
}

template<int C>
__global__ __launch_bounds__(256)
void k_knnstd(const float* __restrict__ x,
              const float* __restrict__ xs, const float* __restrict__ ys, const float* __restrict__ zs,
              const float* __restrict__ nxs, const float* __restrict__ nys, const float* __restrict__ nzs,
              const int* __restrict__ fi, int N, int G,
              int* __restrict__ ki, float* __restrict__ sums){
  extern __shared__ u32 smk[];
  u32* keys = smk;           // N
  u32* hist = smk + N;       // 256
  u32* eq   = hist + 256;    // 512
  u32* sc   = eq + 512;      // [0]=prefix [1]=base [2]=outcnt [3]=eqcnt
  u32* wtot = sc + 4;        // 4 wave totals for the scan
  __shared__ float sLcx[C];
  __shared__ int sKi[KNB];
  __shared__ int sFi;
  __shared__ float sRed[4];
  int tid = threadIdx.x;
  int wv = tid >> 6, lane = tid & 63;
  int g = blockIdx.x % G, b = blockIdx.x / G;
  if (tid==0){ int f0 = fi[g]; if ((u32)f0 >= (u32)N) f0 = 0; sFi = f0; }
  float cx = nxs[b*G+g], cy = nys[b*G+g], cz = nzs[b*G+g];
  float ss = __fadd_rn(__fadd_rn(__fmul_rn(cx,cx), __fmul_rn(cy,cy)), __fmul_rn(cz,cz));
  for (int n = tid; n < N; n += 256){
    float px = xs[b*N+n], py = ys[b*N+n], pz = zs[b*N+n];
    float nn  = __fadd_rn(__fadd_rn(__fmul_rn(px,px), __fmul_rn(py,py)), __fmul_rn(pz,pz));
    float dot = __fadd_rn(__fadd_rn(__fmul_rn(cx,px), __fmul_rn(cy,py)), __fmul_rn(cz,pz));
    float sq  = __fsub_rn(__fadd_rn(ss, nn), __fmul_rn(2.0f, dot));
    u32 u = __float_as_uint(sq);
    keys[n] = (u & 0x80000000u) ? ~u : (u | 0x80000000u);
  }
  if (tid < 4) sc[tid] = 0;
  __syncthreads();
  for (int c = tid; c < C; c += 256) sLcx[c] = x[(size_t)(b*N + sFi)*C + c];
  u32 prefix = 0, bas = 0;
  for (int pass=0; pass<4; pass++){
    int shift = 24 - 8*pass;
    u32 mask = (pass==0) ? 0u : (0xFFFFFFFFu << (shift+8));
    hist[tid] = 0;
    __syncthreads();
    for (int n = tid; n < N; n += 256){
      u32 k = keys[n];
      if ((k & mask) == (prefix & mask))
        atomicAdd(&hist[(k >> shift) & 255u], 1u);
    }
    __syncthreads();
    u32 h = hist[tid];
    u32 p = h;
    #pragma unroll
    for (int off=1; off<64; off<<=1){
      u32 o = __shfl_up(p, off, 64);
      if (lane >= off) p += o;
    }
    if (lane == 63) wtot[wv] = p;
    __syncthreads();
    u32 ex = p - h;
    for (int w2=0; w2<wv; w2++) ex += wtot[w2];
    if (bas + ex < KNB && bas + ex + h >= KNB){
      sc[0] = prefix | ((u32)tid << shift);
      sc[1] = bas + ex;
    }
    __syncthreads();
    prefix = sc[0]; bas = sc[1];
    __syncthreads();
  }
  u32 T = prefix;
  int needEq = KNB - (int)bas;
  int* out = ki + (size_t)(b*G+g)*KNB;
  for (int n = tid; n < N; n += 256){
    u32 k = keys[n];
    if (k < T){
      u32 p2 = atomicAdd(&sc[2], 1u);
      if (p2 < KNB){ out[p2] = n; sKi[p2] = n; }
    } else if (k == T){
      u32 e = atomicAdd(&sc[3], 1u);
      if (e < 512) eq[e] = (u32)n;
    }
  }
  __syncthreads();
  int m = (int)sc[3]; if (m > 512) m = 512;
  for (int i = tid; i < m; i += 256){
    u32 v = eq[i];
    int r = 0;
    for (int j=0; j<m; j++) r += (eq[j] < v);
    if (r < needEq){
      u32 p2 = atomicAdd(&sc[2], 1u);
      if (p2 < KNB){ out[p2] = (int)v; sKi[p2] = (int)v; }
    }
  }
  __syncthreads();
  if (tid == 0){
    u32 c = sc[2];
    while (c < KNB){ out[c] = 0; sKi[c] = 0; c++; }
  }
  __syncthreads();
  // ---- std partial sums over the selected neighbors ----
  float s1=0, s2=0, s3=0, s4=0;
  constexpr int C2 = C/2;
  for (int u2 = tid; u2 < KNB*C2; u2 += 256){
    int k = u2 / C2; int c = (u2 - k*C2)*2;
    int idx = sKi[k];
    float2 v = *(const float2*)(x + (size_t)(b*N + idx)*C + c);
    float a0 = v.x - sLcx[c];
    float a1 = v.y - sLcx[c+1];
    s1 += a0 + a1; s2 += a0*a0 + a1*a1;
  }
  if (tid < 3){
    for (int k=0;k<KNB;k++){
      int idx = sKi[k];
      float pc = (tid==0 ? xs[b*N+idx] : tid==1 ? ys[b*N+idx] : zs[b*N+idx]);
      float cc = (tid==0 ? cx : tid==1 ? cy : cz);
      float w = pc - cc;
      s3 += w; s4 += w*w;
    }
  }
  float t;
  t = blockReduceSum(s1, sRed); if (tid==0) atomicAdd(&sums[0], t);
  t = blockReduceSum(s2, sRed); if (tid==0) atomicAdd(&sums[1], t);
  t = blockReduceSum(s3, sRed); if (tid==0) atomicAdd(&sums[2], t);
  t = blockReduceSum(s4, sRed); if (tid==0) atomicAdd(&sums[3], t);
}

// ---------------- main feature kernel: w = (feat+pe)*pe, max+mean over K ----------------
// inv (1/(std+eps)) computed in-block from sums.
template<int C>
__global__ void k_feat(const float* __restrict__ x,
            const float* __restrict__ xs, const float* __restrict__ ys, const float* __restrict__ zs,
            const float* __restrict__ nxs, const float* __restrict__ nys, const float* __restrict__ nzs,
            const int* __restrict__ fi, const int* __restrict__ ki, const float* __restrict__ sums,
            double n1, double n2,
            int N, int G, float* __restrict__ lc){
  constexpr int D = 2*C;
  constexpr int D3 = D/3;
  constexpr int FD = C/3;
  __shared__ float sLcx[C];
  __shared__ float sDx[KNB*3];
  __shared__ int sKi[KNB];
  __shared__ int sFi;
  __shared__ float sC[3];
  __shared__ float sInv2[2];
  int tid = threadIdx.x;
  int g = blockIdx.x % G, b = blockIdx.x / G;
  if (tid==0){ int f0 = fi[g]; if ((u32)f0 >= (u32)N) f0 = 0; sFi = f0; }
  if (tid==0){
    double s1 = sums[0], s2 = sums[1];
    double mean = s1/n1;
    double var = (s2 - s1*mean)/(n1 - 1.0); if (var < 0) var = 0;
    sInv2[0] = (float)(1.0/(sqrt(var) + 1e-5));
    double t1 = sums[2], t2 = sums[3];
    double m2 = t1/n2;
    double v2 = (t2 - t1*m2)/(n2 - 1.0); if (v2 < 0) v2 = 0;
    sInv2[1] = (float)(1.0/(sqrt(v2) + 1e-5));
  }
  if (tid<3) sC[tid] = (tid==0 ? nxs[b*G+g] : tid==1 ? nys[b*G+g] : nzs[b*G+g]);
  if (tid < KNB){ int v = ki[(size_t)(b*G+g)*KNB + tid]; if ((u32)v >= (u32)N) v = 0; sKi[tid] = v; }
  __syncthreads();
  for (int c = tid; c < C; c += blockDim.x) sLcx[c] = x[(size_t)(b*N + sFi)*C + c];
  for (int t = tid; t < KNB*3; t += blockDim.x){
    int k = t/3, c = t%3;
    int idx = sKi[k];
    float pc = (c==0 ? xs[b*N+idx] : c==1 ? ys[b*N+idx] : zs[b*N+idx]);
    sDx[t] = (pc - sC[c]) * sInv2[1];
  }
  __syncthreads();
  int p = tid;
  if (p >= C) return;
  int d0 = 2*p;
  int c = d0 / D3;
  int f = (d0 - c*D3) >> 1;
  float rcp = __powf(1000.0f, -(float)f / (float)FD);
  bool low = (d0 < C);
  float invdx = sInv2[0];
  float fh0 = 0.f, fh1 = 0.f;
  if (!low){ fh0 = sLcx[d0-C]; fh1 = sLcx[d0+1-C]; }
  float l0 = low ? sLcx[d0] : 0.f, l1 = low ? sLcx[d0+1] : 0.f;
  float mx0=-INFINITY, mx1=-INFINITY, sm0=0.f, sm1=0.f;
  for (int k=0;k<KNB;k++){
    float a = (100.0f * sDx[k*3+c]) * rcp;
    float sn, cs; __sincosf(a, &sn, &cs);
    float f0, f1;
    if (low){
      float2 v = *(const float2*)(x + (size_t)(b*N + sKi[k])*C + d0);
      f0 = (v.x - l0) * invdx;
      f1 = (v.y - l1) * invdx;
    } else { f0 = fh0; f1 = fh1; }
    float w0 = (f0 + sn)*sn;
    float w1 = (f1 + cs)*cs;
    mx0 = fmaxf(mx0, w0); sm0 += w0;
    mx1 = fmaxf(mx1, w1); sm1 += w1;
  }
  float* o = lc + (size_t)(b*G+g)*D + d0;
  o[0] = mx0 + sm0/90.0f;
  o[1] = mx1 + sm1/90.0f;
}

// ---------------- fused BatchNorm stats + apply + GELU (in-place) ----------------
__global__ __launch_bounds__(256)
void k_bnapply(float* __restrict__ lc, const float* __restrict__ gamma,
               const float* __restrict__ beta, int D, int M){
  __shared__ double sS[4][64], sQ[4][64];
  __shared__ float sA[64], sB[64];
  int lane = threadIdx.x & 63, row = threadIdx.x >> 6;
  int d = blockIdx.x*64 + lane;
  double s=0, q=0;
  if (d < D){
    for (int i=row; i<M; i+=4){
      float v = lc[(size_t)i*D + d];
      s += v; q += (double)v*v;
    }
  }
  sS[row][lane]=s; sQ[row][lane]=q;
  __syncthreads();
  if (row==0 && d < D){
    double ts = sS[0][lane]+sS[1][lane]+sS[2][lane]+sS[3][lane];
    double tq = sQ[0][lane]+sQ[1][lane]+sQ[2][lane]+sQ[3][lane];
    double mean = ts / M;
    double var = tq / M - mean*mean; if (var < 0) var = 0;
    float rstd = (float)(1.0/sqrt(var + 1e-5));
    float gm = gamma[d], bt = beta[d];
    sA[lane] = gm*rstd;
    sB[lane] = bt - (float)mean*gm*rstd;
  }
  __syncthreads();
  if (d < D){
    float A = sA[lane], Bv = sB[lane];
    for (int i=row; i<M; i+=4){
      float v = lc[(size_t)i*D + d]*A + Bv;
      lc[(size_t)i*D + d] = 0.5f * v * (1.0f + erff(v * 0.70710678118654752f));
    }
  }
}

__global__ void k_out(const float* __restrict__ feat, float* __restrict__ out){
  int i = blockIdx.x*blockDim.x + threadIdx.x;
  if (i >= BB*1152) return;
  int b = i / 1152, d = i % 1152;
  const float* base = feat + (size_t)b*256*1152 + d;
  float mx = -INFINITY, sm = 0.f;
  for (int g=0; g<256; g++){
    float v = base[(size_t)g*1152];
    mx = fmaxf(mx, v); sm += v;
  }
  out[i] = mx + sm/256.0f;
}

// ---------------- launch ----------------
extern "C" void kernel_launch(void* const* d_in, const int* in_sizes, int n_in,
                              void* d_out, int out_size, void* d_ws, size_t ws_size,
                              hipStream_t stream) {
  const float* xyz = (const float*)d_in[0];
  const float* xin = (const float*)d_in[1];
  float* ws = (float*)d_ws;
  size_t off = 0;
  const size_t PS = (size_t)BB*NP0;
  const size_t XS = (size_t)BB*NP0*CC0;
  float* pA[3]; float* pB[3];
  for (int i=0;i<3;i++){ pA[i] = ws + off; off += PS; }
  for (int i=0;i<3;i++){ pB[i] = ws + off; off += PS; }
  float* xA = ws + off; off += XS;
  float* xB = ws + off; off += XS;
  int*   fi = (int*)(ws + off); off += 2048;
  int*   ki = (int*)(ws + off); off += (size_t)BB*2048*KNB;
  float* sums = ws + off; off += 16;

  k_init<<<(BB*NP0*36+255)/256, 256, 0, stream>>>(xyz, xin, pA[0], pA[1], pA[2], xA);

  float *cx=pA[0], *cy=pA[1], *cz=pA[2], *nx=pB[0], *ny=pB[1], *nz=pB[2];
  float *xc=xA, *lc=xB;
  for (int s=0; s<4; s++){
    int N = NP0 >> s, G = N >> 1, C = CC0 << s, D = 2*C;
    if (s==0)      k_fps4<16><<<1, 256, 0, stream>>>(cx,cy,cz, N, G, fi, nx,ny,nz, sums);
    else if (s==1) k_fps4<8><<<1, 256, 0, stream>>>(cx,cy,cz, N, G, fi, nx,ny,nz, sums);
    else if (s==2) k_fps1<16><<<1, 64, 0, stream>>>(cx,cy,cz, N, G, fi, nx,ny,nz, sums);
    else           k_fps1<8><<<1, 64, 0, stream>>>(cx,cy,cz, N, G, fi, nx,ny,nz, sums);
    size_t knn_lds = (size_t)(N + 256 + 512 + 8 + 8)*4;
    if (s==0)      k_knnstd<72 ><<<BB*G, 256, knn_lds, stream>>>(xc, cx,cy,cz, nx,ny,nz, fi, N, G, ki, sums);
    else if (s==1) k_knnstd<144><<<BB*G, 256, knn_lds, stream>>>(xc, cx,cy,cz, nx,ny,nz, fi, N, G, ki, sums);
    else if (s==2) k_knnstd<288><<<BB*G, 256, knn_lds, stream>>>(xc, cx,cy,cz, nx,ny,nz, fi, N, G, ki, sums);
    else           k_knnstd<576><<<BB*G, 256, knn_lds, stream>>>(xc, cx,cy,cz, nx,ny,nz, fi, N, G, ki, sums);
    double n1 = (double)BB*G*KNB*C, n2 = (double)BB*G*KNB*3;
    int Tp = ((C + 63)/64)*64;
    if (s==0)      k_feat<72 ><<<BB*G, Tp, 0, stream>>>(xc, cx,cy,cz, nx,ny,nz, fi, ki, sums, n1, n2, N, G, lc);
    else if (s==1) k_feat<144><<<BB*G, Tp, 0, stream>>>(xc, cx,cy,cz, nx,ny,nz, fi, ki, sums, n1, n2, N, G, lc);
    else if (s==2) k_feat<288><<<BB*G, Tp, 0, stream>>>(xc, cx,cy,cz, nx,ny,nz, fi, ki, sums, n1, n2, N, G, lc);
    else           k_feat<576><<<BB*G, Tp, 0, stream>>>(xc, cx,cy,cz, nx,ny,nz, fi, ki, sums, n1, n2, N, G, lc);
    k_bnapply<<<(D + 63)/64, 256, 0, stream>>>(lc, (const float*)d_in[2+2*s],
                                               (const float*)d_in[3+2*s], D, BB*G);
    float* t;
    t=cx; cx=nx; nx=t;  t=cy; cy=ny; ny=t;  t=cz; cz=nz; nz=t;
    t=xc; xc=lc; lc=t;
  }
  k_out<<<(BB*1152+255)/256, 256, 0, stream>>>(xc, (float*)d_out);
}

// Round 12
// 4138.301 us; speedup vs baseline: 1.2432x; 1.2432x over previous
//
#include <hip/hip_runtime.h>

typedef unsigned int u32;
typedef unsigned long long u64;
typedef float v2f __attribute__((ext_vector_type(2)));

#define BB 4
#define NP0 4096
#define KNB 90
#define CC0 72

// ---------------- fused input conversion ----------------
__global__ void k_init(const float* __restrict__ xyz, const float* __restrict__ x,
                       float* __restrict__ xs, float* __restrict__ ys, float* __restrict__ zs,
                       float* __restrict__ feat){
  int i = blockIdx.x*blockDim.x + threadIdx.x;
  if (i < BB*NP0){
    xs[i] = xyz[3*i+0];
    ys[i] = xyz[3*i+1];
    zs[i] = xyz[3*i+2];
  }
  if (i < BB*NP0*36){
    int j = i % 36; int bn = i / 36;
    int n = bn % NP0, b = bn / NP0;
    int cin = j / 12, f = j % 12;
    float xv = x[(b*3+cin)*NP0 + n];
    float rcp = __powf(1000.0f, -(float)f / 12.0f);
    float a = (100.0f * xv) * rcp;
    float sn, cs; __sincosf(a, &sn, &cs);
    float2 v = make_float2(sn, cs);
    *(float2*)(feat + (size_t)bn*CC0 + cin*24 + 2*f) = v;
  }
}

// Wave64 argmax: DPP fmax chain -> readlane(63) for max; ballot+ffs -> winning
// lane (smallest lane = smallest global index, jnp.argmax tie rule); readlane
// for the index. No ds_bpermute anywhere.
__device__ __forceinline__ void wave_argmax(float bd, int bi, float &smax, int &wbi){
  float v = bd;
  #define DPP_MAX(ctrl) do{ int _t = __builtin_amdgcn_mov_dpp(__float_as_int(v), (ctrl), 0xf, 0xf, true); \
                            v = fmaxf(v, __int_as_float(_t)); }while(0)
  DPP_MAX(0x111); DPP_MAX(0x112); DPP_MAX(0x114); DPP_MAX(0x118); // row_shr 1,2,4,8
  DPP_MAX(0x142); DPP_MAX(0x143);                                 // row_bcast15, row_bcast31
  #undef DPP_MAX
  smax = __int_as_float(__builtin_amdgcn_readlane(__float_as_int(v), 63));
  u64 msk = __ballot(bd == smax);
  int winlane = (int)__ffsll((long long)msk) - 1;
  wbi = __builtin_amdgcn_readlane(bi, winlane);
}

// ---------------- FPS (exact, batch 0) ----------------
// Packed-fp32 distance update (v_pk ops are IEEE rn per lane, association
// (dx^2+dy^2)+dz^2 preserved, contract(off) -> bit-identical to numpy f32).
// Within-thread strict > keeps smallest index on ties (even element first).
// NOTE: no winner-coord tracking in dist loop (R6: VGPR spill).

// 4-wave version (stages 0,1): 256 thr, PPT=N/256. Also zeroes sums[0..3].
template<int PPT>
__global__ __launch_bounds__(256)
void k_fps4(const float* __restrict__ xs, const float* __restrict__ ys, const float* __restrict__ zs,
            int N, int G, int* __restrict__ fi,
            float* __restrict__ nxs, float* __restrict__ nys, float* __restrict__ nzs,
            float* __restrict__ sums){
  constexpr int PH = PPT/2;
  __shared__ float4 sp[4096];
  __shared__ int sfi[2048];
  __shared__ u64 cand[2][4];
  int tid = threadIdx.x;
  const int base = tid * PPT;
  int wv = tid >> 6;
  int lane = tid & 63;
  if (tid < 4) sums[tid] = 0.f;
  v2f px[PH], py[PH], pz[PH], dmn[PH];
  #pragma unroll
  for (int j=0;j<PH;j++){
    int n = base + 2*j;
    float2 ax = *(const float2*)(xs+n);
    float2 ay = *(const float2*)(ys+n);
    float2 az = *(const float2*)(zs+n);
    px[j] = (v2f){ax.x, ax.y};
    py[j] = (v2f){ay.x, ay.y};
    pz[j] = (v2f){az.x, az.y};
    sp[n]   = make_float4(ax.x, ay.x, az.x, 0.f);
    sp[n+1] = make_float4(ax.y, ay.y, az.y, 0.f);
    dmn[j] = (v2f){INFINITY, INFINITY};
  }
  if (tid==0){ sfi[0]=0; }
  float lx = xs[0], ly = ys[0], lz = zs[0];
  __syncthreads();
  for (int t=1; t<G; t++){
    float bd = -INFINITY; int bi = base;
    v2f lx2 = (v2f){lx,lx}, ly2 = (v2f){ly,ly}, lz2 = (v2f){lz,lz};
    {
      #pragma clang fp contract(off)
      #pragma unroll
      for (int j=0;j<PH;j++){
        v2f dx = px[j] - lx2;
        v2f dy = py[j] - ly2;
        v2f dz = pz[j] - lz2;
        v2f d2 = (dx*dx + dy*dy) + dz*dz;
        v2f dmo = dmn[j];
        float dm0 = fminf(dmo.x, d2.x);
        float dm1 = fminf(dmo.y, d2.y);
        dmn[j] = (v2f){dm0, dm1};
        bool g0 = dm0 > bd;
        bd = g0 ? dm0 : bd;
        bi = g0 ? (base + 2*j) : bi;
        bool g1 = dm1 > bd;
        bd = g1 ? dm1 : bd;
        bi = g1 ? (base + 2*j + 1) : bi;
      }
    }
    float smax; int wbi;
    wave_argmax(bd, bi, smax, wbi);
    int par = t & 1;
    if (lane == 0) cand[par][wv] = ((u64)__float_as_uint(smax) << 32) | (u32)(~(u32)wbi);
    __syncthreads();
    u64 k0 = cand[par][0], k1 = cand[par][1], k2 = cand[par][2], k3 = cand[par][3];
    u64 ka = k0 > k1 ? k0 : k1;
    u64 kb = k2 > k3 ? k2 : k3;
    u64 km = ka > kb ? ka : kb;
    int w = (int)(~(u32)km);
    if ((u32)w >= (u32)N) w = 0;
    float4 p = sp[w];
    lx = p.x; ly = p.y; lz = p.z;
    if (tid==0){ sfi[t] = w; }
  }
  __syncthreads();
  for (int i = tid; i < G; i += 256) fi[i] = sfi[i];
  for (int i = tid; i < BB*G; i += 256){
    int b = i / G, g = i % G;
    int idx = sfi[g];
    nxs[i] = xs[(size_t)b*N + idx];
    nys[i] = ys[(size_t)b*N + idx];
    nzs[i] = zs[(size_t)b*N + idx];
  }
}

// single-wave version (stages 2,3): 64 thr, PPT=N/64. NO barriers, NO exchange.
template<int PPT>
__global__ __launch_bounds__(64, 1)
void k_fps1(const float* __restrict__ xs, const float* __restrict__ ys, const float* __restrict__ zs,
            int N, int G, int* __restrict__ fi,
            float* __restrict__ nxs, float* __restrict__ nys, float* __restrict__ nzs,
            float* __restrict__ sums){
  constexpr int PH = PPT/2;
  __shared__ float4 sp[1024];
  __shared__ int sfi[512];
  int tid = threadIdx.x;
  const int base = tid * PPT;
  if (tid < 4) sums[tid] = 0.f;
  v2f px[PH], py[PH], pz[PH], dmn[PH];
  #pragma unroll
  for (int j=0;j<PH;j++){
    int n = base + 2*j;
    float2 ax = *(const float2*)(xs+n);
    float2 ay = *(const float2*)(ys+n);
    float2 az = *(const float2*)(zs+n);
    px[j] = (v2f){ax.x, ax.y};
    py[j] = (v2f){ay.x, ay.y};
    pz[j] = (v2f){az.x, az.y};
    sp[n]   = make_float4(ax.x, ay.x, az.x, 0.f);
    sp[n+1] = make_float4(ax.y, ay.y, az.y, 0.f);
    dmn[j] = (v2f){INFINITY, INFINITY};
  }
  if (tid==0){ sfi[0]=0; }
  float lx = xs[0], ly = ys[0], lz = zs[0];
  __syncthreads();  // one wave: cheap; orders staging writes before dynamic reads
  for (int t=1; t<G; t++){
    float bd = -INFINITY; int bi = base;
    v2f lx2 = (v2f){lx,lx}, ly2 = (v2f){ly,ly}, lz2 = (v2f){lz,lz};
    {
      #pragma clang fp contract(off)
      #pragma unroll
      for (int j=0;j<PH;j++){
        v2f dx = px[j] - lx2;
        v2f dy = py[j] - ly2;
        v2f dz = pz[j] - lz2;
        v2f d2 = (dx*dx + dy*dy) + dz*dz;
        v2f dmo = dmn[j];
        float dm0 = fminf(dmo.x, d2.x);
        float dm1 = fminf(dmo.y, d2.y);
        dmn[j] = (v2f){dm0, dm1};
        bool g0 = dm0 > bd;
        bd = g0 ? dm0 : bd;
        bi = g0 ? (base + 2*j) : bi;
        bool g1 = dm1 > bd;
        bd = g1 ? dm1 : bd;
        bi = g1 ? (base + 2*j + 1) : bi;
      }
    }
    float smax; int w;
    wave_argmax(bd, bi, smax, w);
    if ((u32)w >= (u32)N) w = 0;
    float4 p = sp[w];
    lx = p.x; ly = p.y; lz = p.z;
    if (tid==0){ sfi[t] = w; }
  }
  for (int i = tid; i < G; i += 64) fi[i] = sfi[i];
  for (int i = tid; i < BB*G; i += 64){
    int b = i / G, g = i % G;
    int idx = sfi[g];
    nxs[i] = xs[(size_t)b*N + idx];
    nys[i] = ys[(size_t)b*N + idx];
    nzs[i] = zs[(size_t)b*N + idx];
  }
}

// ---------------- fused kNN (exact radix select) + std partial sums ----------------
__device__ float blockReduceSum(float v, float* sRed){
  for (int off=32; off; off>>=1) v += __shfl_down(v, off, 64);
  int wid = threadIdx.x >> 6, lane = threadIdx.x & 63;
  __syncthreads();
  if (lane==0) sRed[wid] = v;
  __syncthreads();
  float r = 0;
  if (threadIdx.x == 0){ for (int i=0;i<4;i++) r += sRed[i]; }
  return r;
}

template<int C>
__global__ __launch_bounds__(256)
void k_knnstd(const float* __restrict__ x,
              const float* __restrict__ xs, const float* __restrict__ ys, const float* __restrict__ zs,
              const float* __restrict__ nxs, const float* __restrict__ nys, const float* __restrict__ nzs,
              const int* __restrict__ fi, int N, int G,
              int* __restrict__ ki, float* __restrict__ sums){
  extern __shared__ u32 smk[];
  u32* keys = smk;           // N
  u32* hist = smk + N;       // 256
  u32* eq   = hist + 256;    // 512
  u32* sc   = eq + 512;      // [0]=prefix [1]=base [2]=outcnt [3]=eqcnt
  u32* wtot = sc + 4;        // 4 wave totals for the scan
  __shared__ float sLcx[C];
  __shared__ int sKi[KNB];
  __shared__ int sFi;
  __shared__ float sRed[4];
  int tid = threadIdx.x;
  int wv = tid >> 6, lane = tid & 63;
  int g = blockIdx.x % G, b = blockIdx.x / G;
  if (tid==0){ int f0 = fi[g]; if ((u32)f0 >= (u32)N) f0 = 0; sFi = f0; }
  float cx = nxs[b*G+g], cy = nys[b*G+g], cz = nzs[b*G+g];
  float ss = __fadd_rn(__fadd_rn(__fmul_rn(cx,cx), __fmul_rn(cy,cy)), __fmul_rn(cz,cz));
  for (int n = tid; n < N; n += 256){
    float px = xs[b*N+n], py = ys[b*N+n], pz = zs[b*N+n];
    float nn  = __fadd_rn(__fadd_rn(__fmul_rn(px,px), __fmul_rn(py,py)), __fmul_rn(pz,pz));
    float dot = __fadd_rn(__fadd_rn(__fmul_rn(cx,px), __fmul_rn(cy,py)), __fmul_rn(cz,pz));
    float sq  = __fsub_rn(__fadd_rn(ss, nn), __fmul_rn(2.0f, dot));
    u32 u = __float_as_uint(sq);
    keys[n] = (u & 0x80000000u) ? ~u : (u | 0x80000000u);
  }
  if (tid < 4) sc[tid] = 0;
  __syncthreads();
  for (int c = tid; c < C; c += 256) sLcx[c] = x[(size_t)(b*N + sFi)*C + c];
  u32 prefix = 0, bas = 0;
  for (int pass=0; pass<4; pass++){
    int shift = 24 - 8*pass;
    u32 mask = (pass==0) ? 0u : (0xFFFFFFFFu << (shift+8));
    hist[tid] = 0;
    __syncthreads();
    for (int n = tid; n < N; n += 256){
      u32 k = keys[n];
      if ((k & mask) == (prefix & mask))
        atomicAdd(&hist[(k >> shift) & 255u], 1u);
    }
    __syncthreads();
    u32 h = hist[tid];
    u32 p = h;
    #pragma unroll
    for (int off=1; off<64; off<<=1){
      u32 o = __shfl_up(p, off, 64);
      if (lane >= off) p += o;
    }
    if (lane == 63) wtot[wv] = p;
    __syncthreads();
    u32 ex = p - h;
    for (int w2=0; w2<wv; w2++) ex += wtot[w2];
    if (bas + ex < KNB && bas + ex + h >= KNB){
      sc[0] = prefix | ((u32)tid << shift);
      sc[1] = bas + ex;
    }
    __syncthreads();
    prefix = sc[0]; bas = sc[1];
    __syncthreads();
  }
  u32 T = prefix;
  int needEq = KNB - (int)bas;
  int* out = ki + (size_t)(b*G+g)*KNB;
  for (int n = tid; n < N; n += 256){
    u32 k = keys[n];
    if (k < T){
      u32 p2 = atomicAdd(&sc[2], 1u);
      if (p2 < KNB){ out[p2] = n; sKi[p2] = n; }
    } else if (k == T){
      u32 e = atomicAdd(&sc[3], 1u);
      if (e < 512) eq[e] = (u32)n;
    }
  }
  __syncthreads();
  int m = (int)sc[3]; if (m > 512) m = 512;
  for (int i = tid; i < m; i += 256){
    u32 v = eq[i];
    int r = 0;
    for (int j=0; j<m; j++) r += (eq[j] < v);
    if (r < needEq){
      u32 p2 = atomicAdd(&sc[2], 1u);
      if (p2 < KNB){ out[p2] = (int)v; sKi[p2] = (int)v; }
    }
  }
  __syncthreads();
  if (tid == 0){
    u32 c = sc[2];
    while (c < KNB){ out[c] = 0; sKi[c] = 0; c++; }
  }
  __syncthreads();
  // ---- std partial sums over the selected neighbors ----
  float s1=0, s2=0, s3=0, s4=0;
  constexpr int C2 = C/2;
  for (int u2 = tid; u2 < KNB*C2; u2 += 256){
    int k = u2 / C2; int c = (u2 - k*C2)*2;
    int idx = sKi[k];
    float2 v = *(const float2*)(x + (size_t)(b*N + idx)*C + c);
    float a0 = v.x - sLcx[c];
    float a1 = v.y - sLcx[c+1];
    s1 += a0 + a1; s2 += a0*a0 + a1*a1;
  }
  if (tid < 3){
    for (int k=0;k<KNB;k++){
      int idx = sKi[k];
      float pc = (tid==0 ? xs[b*N+idx] : tid==1 ? ys[b*N+idx] : zs[b*N+idx]);
      float cc = (tid==0 ? cx : tid==1 ? cy : cz);
      float w = pc - cc;
      s3 += w; s4 += w*w;
    }
  }
  float t;
  t = blockReduceSum(s1, sRed); if (tid==0) atomicAdd(&sums[0], t);
  t = blockReduceSum(s2, sRed); if (tid==0) atomicAdd(&sums[1], t);
  t = blockReduceSum(s3, sRed); if (tid==0) atomicAdd(&sums[2], t);
  t = blockReduceSum(s4, sRed); if (tid==0) atomicAdd(&sums[3], t);
}

// ---------------- main feature kernel: w = (feat+pe)*pe, max+mean over K ----------------
// inv (1/(std+eps)) computed in-block from sums.
template<int C>
__global__ void k_feat(const float* __restrict__ x,
            const float* __restrict__ xs, const float* __restrict__ ys, const float* __restrict__ zs,
            const float* __restrict__ nxs, const float* __restrict__ nys, const float* __restrict__ nzs,
            const int* __restrict__ fi, const int* __restrict__ ki, const float* __restrict__ sums,
            double n1, double n2,
            int N, int G, float* __restrict__ lc){
  constexpr int D = 2*C;
  constexpr int D3 = D/3;
  constexpr int FD = C/3;
  __shared__ float sLcx[C];
  __shared__ float sDx[KNB*3];
  __shared__ int sKi[KNB];
  __shared__ int sFi;
  __shared__ float sC[3];
  __shared__ float sInv2[2];
  int tid = threadIdx.x;
  int g = blockIdx.x % G, b = blockIdx.x / G;
  if (tid==0){ int f0 = fi[g]; if ((u32)f0 >= (u32)N) f0 = 0; sFi = f0; }
  if (tid==0){
    double s1 = sums[0], s2 = sums[1];
    double mean = s1/n1;
    double var = (s2 - s1*mean)/(n1 - 1.0); if (var < 0) var = 0;
    sInv2[0] = (float)(1.0/(sqrt(var) + 1e-5));
    double t1 = sums[2], t2 = sums[3];
    double m2 = t1/n2;
    double v2 = (t2 - t1*m2)/(n2 - 1.0); if (v2 < 0) v2 = 0;
    sInv2[1] = (float)(1.0/(sqrt(v2) + 1e-5));
  }
  if (tid<3) sC[tid] = (tid==0 ? nxs[b*G+g] : tid==1 ? nys[b*G+g] : nzs[b*G+g]);
  if (tid < KNB){ int v = ki[(size_t)(b*G+g)*KNB + tid]; if ((u32)v >= (u32)N) v = 0; sKi[tid] = v; }
  __syncthreads();
  for (int c = tid; c < C; c += blockDim.x) sLcx[c] = x[(size_t)(b*N + sFi)*C + c];
  for (int t = tid; t < KNB*3; t += blockDim.x){
    int k = t/3, c = t%3;
    int idx = sKi[k];
    float pc = (c==0 ? xs[b*N+idx] : c==1 ? ys[b*N+idx] : zs[b*N+idx]);
    sDx[t] = (pc - sC[c]) * sInv2[1];
  }
  __syncthreads();
  int p = tid;
  if (p >= C) return;
  int d0 = 2*p;
  int c = d0 / D3;
  int f = (d0 - c*D3) >> 1;
  float rcp = __powf(1000.0f, -(float)f / (float)FD);
  bool low = (d0 < C);
  float invdx = sInv2[0];
  float fh0 = 0.f, fh1 = 0.f;
  if (!low){ fh0 = sLcx[d0-C]; fh1 = sLcx[d0+1-C]; }
  float l0 = low ? sLcx[d0] : 0.f, l1 = low ? sLcx[d0+1] : 0.f;
  float mx0=-INFINITY, mx1=-INFINITY, sm0=0.f, sm1=0.f;
  for (int k=0;k<KNB;k++){
    float a = (100.0f * sDx[k*3+c]) * rcp;
    float sn, cs; __sincosf(a, &sn, &cs);
    float f0, f1;
    if (low){
      float2 v = *(const float2*)(x + (size_t)(b*N + sKi[k])*C + d0);
      f0 = (v.x - l0) * invdx;
      f1 = (v.y - l1) * invdx;
    } else { f0 = fh0; f1 = fh1; }
    float w0 = (f0 + sn)*sn;
    float w1 = (f1 + cs)*cs;
    mx0 = fmaxf(mx0, w0); sm0 += w0;
    mx1 = fmaxf(mx1, w1); sm1 += w1;
  }
  float* o = lc + (size_t)(b*G+g)*D + d0;
  o[0] = mx0 + sm0/90.0f;
  o[1] = mx1 + sm1/90.0f;
}

// ---------------- BatchNorm stats (over B,G per channel) ----------------
__global__ __launch_bounds__(256)
void k_bn(const float* __restrict__ lc, const float* __restrict__ gamma,
          const float* __restrict__ beta, int D, int M,
          float* __restrict__ A, float* __restrict__ Bb){
  __shared__ double sS[4][64], sQ[4][64];
  int lane = threadIdx.x & 63, row = threadIdx.x >> 6;
  int d = blockIdx.x*64 + lane;
  double s=0, q=0;
  if (d < D){
    for (int i=row; i<M; i+=4){
      float v = lc[(size_t)i*D + d];
      s += v; q += (double)v*v;
    }
  }
  sS[row][lane]=s; sQ[row][lane]=q;
  __syncthreads();
  if (row==0 && d < D){
    double ts = sS[0][lane]+sS[1][lane]+sS[2][lane]+sS[3][lane];
    double tq = sQ[0][lane]+sQ[1][lane]+sQ[2][lane]+sQ[3][lane];
    double mean = ts / M;
    double var = tq / M - mean*mean; if (var < 0) var = 0;
    float rstd = (float)(1.0/sqrt(var + 1e-5));
    float gm = gamma[d], bt = beta[d];
    A[d] = gm*rstd;
    Bb[d] = bt - (float)mean*gm*rstd;
  }
}

// in-place BN + GELU (lc becomes next-stage feature buffer) — large coalesced grid
__global__ void k_apply(float* __restrict__ lc, const float* __restrict__ A,
                        const float* __restrict__ Bb, int D, int total){
  int i = blockIdx.x*blockDim.x + threadIdx.x;
  if (i >= total) return;
  int d = i % D;
  float v = lc[i]*A[d] + Bb[d];
  lc[i] = 0.5f * v * (1.0f + erff(v * 0.70710678118654752f));
}

__global__ void k_out(const float* __restrict__ feat, float* __restrict__ out){
  int i = blockIdx.x*blockDim.x + threadIdx.x;
  if (i >= BB*1152) return;
  int b = i / 1152, d = i % 1152;
  const float* base = feat + (size_t)b*256*1152 + d;
  float mx = -INFINITY, sm = 0.f;
  for (int g=0; g<256; g++){
    float v = base[(size_t)g*1152];
    mx = fmaxf(mx, v); sm += v;
  }
  out[i] = mx + sm/256.0f;
}

// ---------------- launch ----------------
extern "C" void kernel_launch(void* const* d_in, const int* in_sizes, int n_in,
                              void* d_out, int out_size, void* d_ws, size_t ws_size,
                              hipStream_t stream) {
  const float* xyz = (const float*)d_in[0];
  const float* xin = (const float*)d_in[1];
  float* ws = (float*)d_ws;
  size_t off = 0;
  const size_t PS = (size_t)BB*NP0;
  const size_t XS = (size_t)BB*NP0*CC0;
  float* pA[3]; float* pB[3];
  for (int i=0;i<3;i++){ pA[i] = ws + off; off += PS; }
  for (int i=0;i<3;i++){ pB[i] = ws + off; off += PS; }
  float* xA = ws + off; off += XS;
  float* xB = ws + off; off += XS;
  int*   fi = (int*)(ws + off); off += 2048;
  int*   ki = (int*)(ws + off); off += (size_t)BB*2048*KNB;
  float* sums = ws + off; off += 16;
  float* Abn  = ws + off; off += 1152;
  float* Bbn  = ws + off; off += 1152;

  k_init<<<(BB*NP0*36+255)/256, 256, 0, stream>>>(xyz, xin, pA[0], pA[1], pA[2], xA);

  float *cx=pA[0], *cy=pA[1], *cz=pA[2], *nx=pB[0], *ny=pB[1], *nz=pB[2];
  float *xc=xA, *lc=xB;
  for (int s=0; s<4; s++){
    int N = NP0 >> s, G = N >> 1, C = CC0 << s, D = 2*C;
    if (s==0)      k_fps4<16><<<1, 256, 0, stream>>>(cx,cy,cz, N, G, fi, nx,ny,nz, sums);
    else if (s==1) k_fps4<8><<<1, 256, 0, stream>>>(cx,cy,cz, N, G, fi, nx,ny,nz, sums);
    else if (s==2) k_fps1<16><<<1, 64, 0, stream>>>(cx,cy,cz, N, G, fi, nx,ny,nz, sums);
    else           k_fps1<8><<<1, 64, 0, stream>>>(cx,cy,cz, N, G, fi, nx,ny,nz, sums);
    size_t knn_lds = (size_t)(N + 256 + 512 + 8 + 8)*4;
    if (s==0)      k_knnstd<72 ><<<BB*G, 256, knn_lds, stream>>>(xc, cx,cy,cz, nx,ny,nz, fi, N, G, ki, sums);
    else if (s==1) k_knnstd<144><<<BB*G, 256, knn_lds, stream>>>(xc, cx,cy,cz, nx,ny,nz, fi, N, G, ki, sums);
    else if (s==2) k_knnstd<288><<<BB*G, 256, knn_lds, stream>>>(xc, cx,cy,cz, nx,ny,nz, fi, N, G, ki, sums);
    else           k_knnstd<576><<<BB*G, 256, knn_lds, stream>>>(xc, cx,cy,cz, nx,ny,nz, fi, N, G, ki, sums);
    double n1 = (double)BB*G*KNB*C, n2 = (double)BB*G*KNB*3;
    int Tp = ((C + 63)/64)*64;
    if (s==0)      k_feat<72 ><<<BB*G, Tp, 0, stream>>>(xc, cx,cy,cz, nx,ny,nz, fi, ki, sums, n1, n2, N, G, lc);
    else if (s==1) k_feat<144><<<BB*G, Tp, 0, stream>>>(xc, cx,cy,cz, nx,ny,nz, fi, ki, sums, n1, n2, N, G, lc);
    else if (s==2) k_feat<288><<<BB*G, Tp, 0, stream>>>(xc, cx,cy,cz, nx,ny,nz, fi, ki, sums, n1, n2, N, G, lc);
    else           k_feat<576><<<BB*G, Tp, 0, stream>>>(xc, cx,cy,cz, nx,ny,nz, fi, ki, sums, n1, n2, N, G, lc);
    k_bn<<<(D + 63)/64, 256, 0, stream>>>(lc, (const float*)d_in[2+2*s],
                                          (const float*)d_in[3+2*s], D, BB*G, Abn, Bbn);
    int total = BB*G*D;
    k_apply<<<(total+255)/256, 256, 0, stream>>>(lc, Abn, Bbn, D, total);
    float* t;
    t=cx; cx=nx; nx=t;  t=cy; cy=ny; ny=t;  t=cz; cz=nz; nz=t;
    t=xc; xc=lc; lc=t;
  }
  k_out<<<(BB*1152+255)/256, 256, 0, stream>>>(xc, (float*)d_out);
}

// Round 13
// 3215.083 us; speedup vs baseline: 1.6002x; 1.2872x over previous
//
#include <hip/hip_runtime.h>

typedef unsigned int u32;
typedef unsigned long long u64;
typedef float v2f __attribute__((ext_vector_type(2)));

#define BB 4
#define NP0 4096
#define KNB 90
#define CC0 72
#define MAXD 1152
#define NSTRIPE 16

// ---------------- fused input conversion ----------------
__global__ void k_init(const float* __restrict__ xyz, const float* __restrict__ x,
                       float* __restrict__ xs, float* __restrict__ ys, float* __restrict__ zs,
                       float* __restrict__ feat){
  int i = blockIdx.x*blockDim.x + threadIdx.x;
  if (i < BB*NP0){
    xs[i] = xyz[3*i+0];
    ys[i] = xyz[3*i+1];
    zs[i] = xyz[3*i+2];
  }
  if (i < BB*NP0*36){
    int j = i % 36; int bn = i / 36;
    int n = bn % NP0, b = bn / NP0;
    int cin = j / 12, f = j % 12;
    float xv = x[(b*3+cin)*NP0 + n];
    float rcp = __powf(1000.0f, -(float)f / 12.0f);
    float a = (100.0f * xv) * rcp;
    float sn, cs; __sincosf(a, &sn, &cs);
    float2 v = make_float2(sn, cs);
    *(float2*)(feat + (size_t)bn*CC0 + cin*24 + 2*f) = v;
  }
}

// Wave64 argmax: DPP fmax chain -> readlane(63) for max; ballot+ffs -> winning
// lane (smallest lane = smallest global index, jnp.argmax tie rule); readlane
// for the index. No ds_bpermute anywhere.
__device__ __forceinline__ void wave_argmax(float bd, int bi, float &smax, int &wbi){
  float v = bd;
  #define DPP_MAX(ctrl) do{ int _t = __builtin_amdgcn_mov_dpp(__float_as_int(v), (ctrl), 0xf, 0xf, true); \
                            v = fmaxf(v, __int_as_float(_t)); }while(0)
  DPP_MAX(0x111); DPP_MAX(0x112); DPP_MAX(0x114); DPP_MAX(0x118); // row_shr 1,2,4,8
  DPP_MAX(0x142); DPP_MAX(0x143);                                 // row_bcast15, row_bcast31
  #undef DPP_MAX
  smax = __int_as_float(__builtin_amdgcn_readlane(__float_as_int(v), 63));
  u64 msk = __ballot(bd == smax);
  int winlane = (int)__ffsll((long long)msk) - 1;
  wbi = __builtin_amdgcn_readlane(bi, winlane);
}

// ---------------- FPS (exact, batch 0) ----------------
// Packed-fp32 distance update (v_pk ops are IEEE rn per lane, association
// (dx^2+dy^2)+dz^2 preserved, contract(off) -> bit-identical to numpy f32).
// Within-thread strict > keeps smallest index on ties (even element first).
// NOTE: no winner-coord tracking in dist loop (R6: VGPR spill).

// 4-wave version (stages 0,1): 256 thr, PPT=N/256. Also zeroes sums[0..3].
template<int PPT>
__global__ __launch_bounds__(256)
void k_fps4(const float* __restrict__ xs, const float* __restrict__ ys, const float* __restrict__ zs,
            int N, int G, int* __restrict__ fi,
            float* __restrict__ nxs, float* __restrict__ nys, float* __restrict__ nzs,
            float* __restrict__ sums){
  constexpr int PH = PPT/2;
  __shared__ float4 sp[4096];
  __shared__ int sfi[2048];
  __shared__ u64 cand[2][4];
  int tid = threadIdx.x;
  const int base = tid * PPT;
  int wv = tid >> 6;
  int lane = tid & 63;
  if (tid < 4) sums[tid] = 0.f;
  v2f px[PH], py[PH], pz[PH], dmn[PH];
  #pragma unroll
  for (int j=0;j<PH;j++){
    int n = base + 2*j;
    float2 ax = *(const float2*)(xs+n);
    float2 ay = *(const float2*)(ys+n);
    float2 az = *(const float2*)(zs+n);
    px[j] = (v2f){ax.x, ax.y};
    py[j] = (v2f){ay.x, ay.y};
    pz[j] = (v2f){az.x, az.y};
    sp[n]   = make_float4(ax.x, ay.x, az.x, 0.f);
    sp[n+1] = make_float4(ax.y, ay.y, az.y, 0.f);
    dmn[j] = (v2f){INFINITY, INFINITY};
  }
  if (tid==0){ sfi[0]=0; }
  float lx = xs[0], ly = ys[0], lz = zs[0];
  __syncthreads();
  for (int t=1; t<G; t++){
    float bd = -INFINITY; int bi = base;
    v2f lx2 = (v2f){lx,lx}, ly2 = (v2f){ly,ly}, lz2 = (v2f){lz,lz};
    {
      #pragma clang fp contract(off)
      #pragma unroll
      for (int j=0;j<PH;j++){
        v2f dx = px[j] - lx2;
        v2f dy = py[j] - ly2;
        v2f dz = pz[j] - lz2;
        v2f d2 = (dx*dx + dy*dy) + dz*dz;
        v2f dmo = dmn[j];
        float dm0 = fminf(dmo.x, d2.x);
        float dm1 = fminf(dmo.y, d2.y);
        dmn[j] = (v2f){dm0, dm1};
        bool g0 = dm0 > bd;
        bd = g0 ? dm0 : bd;
        bi = g0 ? (base + 2*j) : bi;
        bool g1 = dm1 > bd;
        bd = g1 ? dm1 : bd;
        bi = g1 ? (base + 2*j + 1) : bi;
      }
    }
    float smax; int wbi;
    wave_argmax(bd, bi, smax, wbi);
    int par = t & 1;
    if (lane == 0) cand[par][wv] = ((u64)__float_as_uint(smax) << 32) | (u32)(~(u32)wbi);
    __syncthreads();
    u64 k0 = cand[par][0], k1 = cand[par][1], k2 = cand[par][2], k3 = cand[par][3];
    u64 ka = k0 > k1 ? k0 : k1;
    u64 kb = k2 > k3 ? k2 : k3;
    u64 km = ka > kb ? ka : kb;
    int w = (int)(~(u32)km);
    if ((u32)w >= (u32)N) w = 0;
    float4 p = sp[w];
    lx = p.x; ly = p.y; lz = p.z;
    if (tid==0){ sfi[t] = w; }
  }
  __syncthreads();
  for (int i = tid; i < G; i += 256) fi[i] = sfi[i];
  for (int i = tid; i < BB*G; i += 256){
    int b = i / G, g = i % G;
    int idx = sfi[g];
    nxs[i] = xs[(size_t)b*N + idx];
    nys[i] = ys[(size_t)b*N + idx];
    nzs[i] = zs[(size_t)b*N + idx];
  }
}

// single-wave version (stages 2,3): 64 thr, PPT=N/64. NO barriers, NO exchange.
template<int PPT>
__global__ __launch_bounds__(64, 1)
void k_fps1(const float* __restrict__ xs, const float* __restrict__ ys, const float* __restrict__ zs,
            int N, int G, int* __restrict__ fi,
            float* __restrict__ nxs, float* __restrict__ nys, float* __restrict__ nzs,
            float* __restrict__ sums){
  constexpr int PH = PPT/2;
  __shared__ float4 sp[1024];
  __shared__ int sfi[512];
  int tid = threadIdx.x;
  const int base = tid * PPT;
  if (tid < 4) sums[tid] = 0.f;
  v2f px[PH], py[PH], pz[PH], dmn[PH];
  #pragma unroll
  for (int j=0;j<PH;j++){
    int n = base + 2*j;
    float2 ax = *(const float2*)(xs+n);
    float2 ay = *(const float2*)(ys+n);
    float2 az = *(const float2*)(zs+n);
    px[j] = (v2f){ax.x, ax.y};
    py[j] = (v2f){ay.x, ay.y};
    pz[j] = (v2f){az.x, az.y};
    sp[n]   = make_float4(ax.x, ay.x, az.x, 0.f);
    sp[n+1] = make_float4(ax.y, ay.y, az.y, 0.f);
    dmn[j] = (v2f){INFINITY, INFINITY};
  }
  if (tid==0){ sfi[0]=0; }
  float lx = xs[0], ly = ys[0], lz = zs[0];
  __syncthreads();  // one wave: cheap; orders staging writes before dynamic reads
  for (int t=1; t<G; t++){
    float bd = -INFINITY; int bi = base;
    v2f lx2 = (v2f){lx,lx}, ly2 = (v2f){ly,ly}, lz2 = (v2f){lz,lz};
    {
      #pragma clang fp contract(off)
      #pragma unroll
      for (int j=0;j<PH;j++){
        v2f dx = px[j] - lx2;
        v2f dy = py[j] - ly2;
        v2f dz = pz[j] - lz2;
        v2f d2 = (dx*dx + dy*dy) + dz*dz;
        v2f dmo = dmn[j];
        float dm0 = fminf(dmo.x, d2.x);
        float dm1 = fminf(dmo.y, d2.y);
        dmn[j] = (v2f){dm0, dm1};
        bool g0 = dm0 > bd;
        bd = g0 ? dm0 : bd;
        bi = g0 ? (base + 2*j) : bi;
        bool g1 = dm1 > bd;
        bd = g1 ? dm1 : bd;
        bi = g1 ? (base + 2*j + 1) : bi;
      }
    }
    float smax; int w;
    wave_argmax(bd, bi, smax, w);
    if ((u32)w >= (u32)N) w = 0;
    float4 p = sp[w];
    lx = p.x; ly = p.y; lz = p.z;
    if (tid==0){ sfi[t] = w; }
  }
  for (int i = tid; i < G; i += 64) fi[i] = sfi[i];
  for (int i = tid; i < BB*G; i += 64){
    int b = i / G, g = i % G;
    int idx = sfi[g];
    nxs[i] = xs[(size_t)b*N + idx];
    nys[i] = ys[(size_t)b*N + idx];
    nzs[i] = zs[(size_t)b*N + idx];
  }
}

// ---------------- fused kNN (exact radix select) + std partial sums ----------------
__device__ float blockReduceSum(float v, float* sRed){
  for (int off=32; off; off>>=1) v += __shfl_down(v, off, 64);
  int wid = threadIdx.x >> 6, lane = threadIdx.x & 63;
  __syncthreads();
  if (lane==0) sRed[wid] = v;
  __syncthreads();
  float r = 0;
  if (threadIdx.x == 0){ for (int i=0;i<4;i++) r += sRed[i]; }
  return r;
}

template<int C>
__global__ __launch_bounds__(256)
void k_knnstd(const float* __restrict__ x,
              const float* __restrict__ xs, const float* __restrict__ ys, const float* __restrict__ zs,
              const float* __restrict__ nxs, const float* __restrict__ nys, const float* __restrict__ nzs,
              const int* __restrict__ fi, int N, int G,
              int* __restrict__ ki, float* __restrict__ sums){
  extern __shared__ u32 smk[];
  u32* keys = smk;           // N
  u32* hist = smk + N;       // 256
  u32* eq   = hist + 256;    // 512
  u32* sc   = eq + 512;      // [0]=prefix [1]=base [2]=outcnt [3]=eqcnt
  u32* wtot = sc + 4;        // 4 wave totals for the scan
  __shared__ float sLcx[C];
  __shared__ int sKi[KNB];
  __shared__ int sFi;
  __shared__ float sRed[4];
  int tid = threadIdx.x;
  int wv = tid >> 6, lane = tid & 63;
  int g = blockIdx.x % G, b = blockIdx.x / G;
  if (tid==0){ int f0 = fi[g]; if ((u32)f0 >= (u32)N) f0 = 0; sFi = f0; }
  float cx = nxs[b*G+g], cy = nys[b*G+g], cz = nzs[b*G+g];
  float ss = __fadd_rn(__fadd_rn(__fmul_rn(cx,cx), __fmul_rn(cy,cy)), __fmul_rn(cz,cz));
  for (int n = tid; n < N; n += 256){
    float px = xs[b*N+n], py = ys[b*N+n], pz = zs[b*N+n];
    float nn  = __fadd_rn(__fadd_rn(__fmul_rn(px,px), __fmul_rn(py,py)), __fmul_rn(pz,pz));
    float dot = __fadd_rn(__fadd_rn(__fmul_rn(cx,px), __fmul_rn(cy,py)), __fmul_rn(cz,pz));
    float sq  = __fsub_rn(__fadd_rn(ss, nn), __fmul_rn(2.0f, dot));
    u32 u = __float_as_uint(sq);
    keys[n] = (u & 0x80000000u) ? ~u : (u | 0x80000000u);
  }
  if (tid < 4) sc[tid] = 0;
  __syncthreads();
  for (int c = tid; c < C; c += 256) sLcx[c] = x[(size_t)(b*N + sFi)*C + c];
  u32 prefix = 0, bas = 0;
  for (int pass=0; pass<4; pass++){
    int shift = 24 - 8*pass;
    u32 mask = (pass==0) ? 0u : (0xFFFFFFFFu << (shift+8));
    hist[tid] = 0;
    __syncthreads();
    for (int n = tid; n < N; n += 256){
      u32 k = keys[n];
      if ((k & mask) == (prefix & mask))
        atomicAdd(&hist[(k >> shift) & 255u], 1u);
    }
    __syncthreads();
    u32 h = hist[tid];
    u32 p = h;
    #pragma unroll
    for (int off=1; off<64; off<<=1){
      u32 o = __shfl_up(p, off, 64);
      if (lane >= off) p += o;
    }
    if (lane == 63) wtot[wv] = p;
    __syncthreads();
    u32 ex = p - h;
    for (int w2=0; w2<wv; w2++) ex += wtot[w2];
    if (bas + ex < KNB && bas + ex + h >= KNB){
      sc[0] = prefix | ((u32)tid << shift);
      sc[1] = bas + ex;
    }
    __syncthreads();
    prefix = sc[0]; bas = sc[1];
    __syncthreads();
  }
  u32 T = prefix;
  int needEq = KNB - (int)bas;
  int* out = ki + (size_t)(b*G+g)*KNB;
  for (int n = tid; n < N; n += 256){
    u32 k = keys[n];
    if (k < T){
      u32 p2 = atomicAdd(&sc[2], 1u);
      if (p2 < KNB){ out[p2] = n; sKi[p2] = n; }
    } else if (k == T){
      u32 e = atomicAdd(&sc[3], 1u);
      if (e < 512) eq[e] = (u32)n;
    }
  }
  __syncthreads();
  int m = (int)sc[3]; if (m > 512) m = 512;
  for (int i = tid; i < m; i += 256){
    u32 v = eq[i];
    int r = 0;
    for (int j=0; j<m; j++) r += (eq[j] < v);
    if (r < needEq){
      u32 p2 = atomicAdd(&sc[2], 1u);
      if (p2 < KNB){ out[p2] = (int)v; sKi[p2] = (int)v; }
    }
  }
  __syncthreads();
  if (tid == 0){
    u32 c = sc[2];
    while (c < KNB){ out[c] = 0; sKi[c] = 0; c++; }
  }
  __syncthreads();
  // ---- std partial sums over the selected neighbors ----
  float s1=0, s2=0, s3=0, s4=0;
  constexpr int C2 = C/2;
  for (int u2 = tid; u2 < KNB*C2; u2 += 256){
    int k = u2 / C2; int c = (u2 - k*C2)*2;
    int idx = sKi[k];
    float2 v = *(const float2*)(x + (size_t)(b*N + idx)*C + c);
    float a0 = v.x - sLcx[c];
    float a1 = v.y - sLcx[c+1];
    s1 += a0 + a1; s2 += a0*a0 + a1*a1;
  }
  if (tid < 3){
    for (int k=0;k<KNB;k++){
      int idx = sKi[k];
      float pc = (tid==0 ? xs[b*N+idx] : tid==1 ? ys[b*N+idx] : zs[b*N+idx]);
      float cc = (tid==0 ? cx : tid==1 ? cy : cz);
      float w = pc - cc;
      s3 += w; s4 += w*w;
    }
  }
  float t;
  t = blockReduceSum(s1, sRed); if (tid==0) atomicAdd(&sums[0], t);
  t = blockReduceSum(s2, sRed); if (tid==0) atomicAdd(&sums[1], t);
  t = blockReduceSum(s3, sRed); if (tid==0) atomicAdd(&sums[2], t);
  t = blockReduceSum(s4, sRed); if (tid==0) atomicAdd(&sums[3], t);
}

// ---------------- main feature kernel: w = (feat+pe)*pe, max+mean over K ----------------
// inv (1/(std+eps)) computed in-block from sums.
template<int C>
__global__ void k_feat(const float* __restrict__ x,
            const float* __restrict__ xs, const float* __restrict__ ys, const float* __restrict__ zs,
            const float* __restrict__ nxs, const float* __restrict__ nys, const float* __restrict__ nzs,
            const int* __restrict__ fi, const int* __restrict__ ki, const float* __restrict__ sums,
            double n1, double n2,
            int N, int G, float* __restrict__ lc){
  constexpr int D = 2*C;
  constexpr int D3 = D/3;
  constexpr int FD = C/3;
  __shared__ float sLcx[C];
  __shared__ float sDx[KNB*3];
  __shared__ int sKi[KNB];
  __shared__ int sFi;
  __shared__ float sC[3];
  __shared__ float sInv2[2];
  int tid = threadIdx.x;
  int g = blockIdx.x % G, b = blockIdx.x / G;
  if (tid==0){ int f0 = fi[g]; if ((u32)f0 >= (u32)N) f0 = 0; sFi = f0; }
  if (tid==0){
    double s1 = sums[0], s2 = sums[1];
    double mean = s1/n1;
    double var = (s2 - s1*mean)/(n1 - 1.0); if (var < 0) var = 0;
    sInv2[0] = (float)(1.0/(sqrt(var) + 1e-5));
    double t1 = sums[2], t2 = sums[3];
    double m2 = t1/n2;
    double v2 = (t2 - t1*m2)/(n2 - 1.0); if (v2 < 0) v2 = 0;
    sInv2[1] = (float)(1.0/(sqrt(v2) + 1e-5));
  }
  if (tid<3) sC[tid] = (tid==0 ? nxs[b*G+g] : tid==1 ? nys[b*G+g] : nzs[b*G+g]);
  if (tid < KNB){ int v = ki[(size_t)(b*G+g)*KNB + tid]; if ((u32)v >= (u32)N) v = 0; sKi[tid] = v; }
  __syncthreads();
  for (int c = tid; c < C; c += blockDim.x) sLcx[c] = x[(size_t)(b*N + sFi)*C + c];
  for (int t = tid; t < KNB*3; t += blockDim.x){
    int k = t/3, c = t%3;
    int idx = sKi[k];
    float pc = (c==0 ? xs[b*N+idx] : c==1 ? ys[b*N+idx] : zs[b*N+idx]);
    sDx[t] = (pc - sC[c]) * sInv2[1];
  }
  __syncthreads();
  int p = tid;
  if (p >= C) return;
  int d0 = 2*p;
  int c = d0 / D3;
  int f = (d0 - c*D3) >> 1;
  float rcp = __powf(1000.0f, -(float)f / (float)FD);
  bool low = (d0 < C);
  float invdx = sInv2[0];
  float fh0 = 0.f, fh1 = 0.f;
  if (!low){ fh0 = sLcx[d0-C]; fh1 = sLcx[d0+1-C]; }
  float l0 = low ? sLcx[d0] : 0.f, l1 = low ? sLcx[d0+1] : 0.f;
  float mx0=-INFINITY, mx1=-INFINITY, sm0=0.f, sm1=0.f;
  for (int k=0;k<KNB;k++){
    float a = (100.0f * sDx[k*3+c]) * rcp;
    float sn, cs; __sincosf(a, &sn, &cs);
    float f0, f1;
    if (low){
      float2 v = *(const float2*)(x + (size_t)(b*N + sKi[k])*C + d0);
      f0 = (v.x - l0) * invdx;
      f1 = (v.y - l1) * invdx;
    } else { f0 = fh0; f1 = fh1; }
    float w0 = (f0 + sn)*sn;
    float w1 = (f1 + cs)*cs;
    mx0 = fmaxf(mx0, w0); sm0 += w0;
    mx1 = fmaxf(mx1, w1); sm1 += w1;
  }
  float* o = lc + (size_t)(b*G+g)*D + d0;
  o[0] = mx0 + sm0/90.0f;
  o[1] = mx1 + sm1/90.0f;
}

// ---------------- BatchNorm: parallel partial stats (grid tiles x stripes) ----------------
__global__ __launch_bounds__(256)
void k_bnpart(const float* __restrict__ lc, int D, int M,
              double* __restrict__ PS, double* __restrict__ PQ){
  __shared__ double sS[4][64], sQ[4][64];
  int lane = threadIdx.x & 63, row = threadIdx.x >> 6;
  int tile = blockIdx.x, stripe = blockIdx.y;
  int d = tile*64 + lane;
  int span = M / NSTRIPE;
  int i0 = stripe * span;
  double s=0, q=0;
  if (d < D){
    for (int i=i0+row; i<i0+span; i+=4){
      float v = lc[(size_t)i*D + d];
      s += v; q += (double)v*v;
    }
  }
  sS[row][lane]=s; sQ[row][lane]=q;
  __syncthreads();
  if (row==0 && d < D){
    PS[(size_t)stripe*MAXD + d] = sS[0][lane]+sS[1][lane]+sS[2][lane]+sS[3][lane];
    PQ[(size_t)stripe*MAXD + d] = sQ[0][lane]+sQ[1][lane]+sQ[2][lane]+sQ[3][lane];
  }
}

__global__ void k_bnfin(const double* __restrict__ PS, const double* __restrict__ PQ,
                        const float* __restrict__ gamma, const float* __restrict__ beta,
                        int D, int M, float* __restrict__ A, float* __restrict__ Bb){
  int d = blockIdx.x*64 + threadIdx.x;
  if (d >= D) return;
  double ts=0, tq=0;
  for (int s=0; s<NSTRIPE; s++){ ts += PS[(size_t)s*MAXD + d]; tq += PQ[(size_t)s*MAXD + d]; }
  double mean = ts / M;
  double var = tq / M - mean*mean; if (var < 0) var = 0;
  float rstd = (float)(1.0/sqrt(var + 1e-5));
  float gm = gamma[d], bt = beta[d];
  A[d] = gm*rstd;
  Bb[d] = bt - (float)mean*gm*rstd;
}

// in-place BN + GELU (lc becomes next-stage feature buffer) — large coalesced grid
__global__ void k_apply(float* __restrict__ lc, const float* __restrict__ A,
                        const float* __restrict__ Bb, int D, int total){
  int i = blockIdx.x*blockDim.x + threadIdx.x;
  if (i >= total) return;
  int d = i % D;
  float v = lc[i]*A[d] + Bb[d];
  lc[i] = 0.5f * v * (1.0f + erff(v * 0.70710678118654752f));
}

__global__ void k_out(const float* __restrict__ feat, float* __restrict__ out){
  int i = blockIdx.x*blockDim.x + threadIdx.x;
  if (i >= BB*1152) return;
  int b = i / 1152, d = i % 1152;
  const float* base = feat + (size_t)b*256*1152 + d;
  float mx = -INFINITY, sm = 0.f;
  for (int g=0; g<256; g++){
    float v = base[(size_t)g*1152];
    mx = fmaxf(mx, v); sm += v;
  }
  out[i] = mx + sm/256.0f;
}

// ---------------- launch ----------------
extern "C" void kernel_launch(void* const* d_in, const int* in_sizes, int n_in,
                              void* d_out, int out_size, void* d_ws, size_t ws_size,
                              hipStream_t stream) {
  const float* xyz = (const float*)d_in[0];
  const float* xin = (const float*)d_in[1];
  float* ws = (float*)d_ws;
  size_t off = 0;
  const size_t PS_ = (size_t)BB*NP0;
  const size_t XS = (size_t)BB*NP0*CC0;
  float* pA[3]; float* pB[3];
  for (int i=0;i<3;i++){ pA[i] = ws + off; off += PS_; }
  for (int i=0;i<3;i++){ pB[i] = ws + off; off += PS_; }
  float* xA = ws + off; off += XS;
  float* xB = ws + off; off += XS;
  int*   fi = (int*)(ws + off); off += 2048;
  int*   ki = (int*)(ws + off); off += (size_t)BB*2048*KNB;
  float* sums = ws + off; off += 16;
  float* Abn  = ws + off; off += 1152;
  float* Bbn  = ws + off; off += 1152;
  off = (off + 1) & ~(size_t)1;  // align to 8B for doubles
  double* PSb = (double*)(ws + off); off += (size_t)NSTRIPE*MAXD*2;
  double* PQb = (double*)(ws + off); off += (size_t)NSTRIPE*MAXD*2;

  k_init<<<(BB*NP0*36+255)/256, 256, 0, stream>>>(xyz, xin, pA[0], pA[1], pA[2], xA);

  float *cx=pA[0], *cy=pA[1], *cz=pA[2], *nx=pB[0], *ny=pB[1], *nz=pB[2];
  float *xc=xA, *lc=xB;
  for (int s=0; s<4; s++){
    int N = NP0 >> s, G = N >> 1, C = CC0 << s, D = 2*C;
    if (s==0)      k_fps4<16><<<1, 256, 0, stream>>>(cx,cy,cz, N, G, fi, nx,ny,nz, sums);
    else if (s==1) k_fps4<8><<<1, 256, 0, stream>>>(cx,cy,cz, N, G, fi, nx,ny,nz, sums);
    else if (s==2) k_fps1<16><<<1, 64, 0, stream>>>(cx,cy,cz, N, G, fi, nx,ny,nz, sums);
    else           k_fps1<8><<<1, 64, 0, stream>>>(cx,cy,cz, N, G, fi, nx,ny,nz, sums);
    size_t knn_lds = (size_t)(N + 256 + 512 + 8 + 8)*4;
    if (s==0)      k_knnstd<72 ><<<BB*G, 256, knn_lds, stream>>>(xc, cx,cy,cz, nx,ny,nz, fi, N, G, ki, sums);
    else if (s==1) k_knnstd<144><<<BB*G, 256, knn_lds, stream>>>(xc, cx,cy,cz, nx,ny,nz, fi, N, G, ki, sums);
    else if (s==2) k_knnstd<288><<<BB*G, 256, knn_lds, stream>>>(xc, cx,cy,cz, nx,ny,nz, fi, N, G, ki, sums);
    else           k_knnstd<576><<<BB*G, 256, knn_lds, stream>>>(xc, cx,cy,cz, nx,ny,nz, fi, N, G, ki, sums);
    double n1 = (double)BB*G*KNB*C, n2 = (double)BB*G*KNB*3;
    int Tp = ((C + 63)/64)*64;
    if (s==0)      k_feat<72 ><<<BB*G, Tp, 0, stream>>>(xc, cx,cy,cz, nx,ny,nz, fi, ki, sums, n1, n2, N, G, lc);
    else if (s==1) k_feat<144><<<BB*G, Tp, 0, stream>>>(xc, cx,cy,cz, nx,ny,nz, fi, ki, sums, n1, n2, N, G, lc);
    else if (s==2) k_feat<288><<<BB*G, Tp, 0, stream>>>(xc, cx,cy,cz, nx,ny,nz, fi, ki, sums, n1, n2, N, G, lc);
    else           k_feat<576><<<BB*G, Tp, 0, stream>>>(xc, cx,cy,cz, nx,ny,nz, fi, ki, sums, n1, n2, N, G, lc);
    int M = BB*G;
    dim3 bng((D + 63)/64, NSTRIPE);
    k_bnpart<<<bng, 256, 0, stream>>>(lc, D, M, PSb, PQb);
    k_bnfin<<<(D + 63)/64, 64, 0, stream>>>(PSb, PQb, (const float*)d_in[2+2*s],
                                            (const float*)d_in[3+2*s], D, M, Abn, Bbn);
    int total = M*D;
    k_apply<<<(total+255)/256, 256, 0, stream>>>(lc, Abn, Bbn, D, total);
    float* t;
    t=cx; cx=nx; nx=t;  t=cy; cy=ny; ny=t;  t=cz; cz=nz; nz=t;
    t=xc; xc=lc; lc=t;
  }
  k_out<<<(BB*1152+255)/256, 256, 0, stream>>>(xc, (float*)d_out);
}

// Round 14
// 2487.793 us; speedup vs baseline: 2.0681x; 1.2923x over previous
//
#include <hip/hip_runtime.h>

typedef unsigned int u32;
typedef unsigned long long u64;
typedef float v2f __attribute__((ext_vector_type(2)));

#define BB 4
#define NP0 4096
#define KNB 90
#define CC0 72
#define MAXD 1152
#define NSTRIPE 16

// ---------------- fused input conversion (+ zero all per-stage sums) ----------------
__global__ void k_init(const float* __restrict__ xyz, const float* __restrict__ x,
                       float* __restrict__ xs, float* __restrict__ ys, float* __restrict__ zs,
                       float* __restrict__ feat, float* __restrict__ sums){
  int i = blockIdx.x*blockDim.x + threadIdx.x;
  if (i < 16) sums[i] = 0.f;
  if (i < BB*NP0){
    xs[i] = xyz[3*i+0];
    ys[i] = xyz[3*i+1];
    zs[i] = xyz[3*i+2];
  }
  if (i < BB*NP0*36){
    int j = i % 36; int bn = i / 36;
    int n = bn % NP0, b = bn / NP0;
    int cin = j / 12, f = j % 12;
    float xv = x[(b*3+cin)*NP0 + n];
    float rcp = __powf(1000.0f, -(float)f / 12.0f);
    float a = (100.0f * xv) * rcp;
    float sn, cs; __sincosf(a, &sn, &cs);
    float2 v = make_float2(sn, cs);
    *(float2*)(feat + (size_t)bn*CC0 + cin*24 + 2*f) = v;
  }
}

// Wave64 argmax: DPP fmax chain -> readlane(63) for max; ballot+ffs -> winning
// lane (smallest lane = smallest global index, jnp.argmax tie rule).
__device__ __forceinline__ void wave_argmax(float bd, int bi, float &smax, int &wbi){
  float v = bd;
  #define DPP_MAX(ctrl) do{ int _t = __builtin_amdgcn_mov_dpp(__float_as_int(v), (ctrl), 0xf, 0xf, true); \
                            v = fmaxf(v, __int_as_float(_t)); }while(0)
  DPP_MAX(0x111); DPP_MAX(0x112); DPP_MAX(0x114); DPP_MAX(0x118);
  DPP_MAX(0x142); DPP_MAX(0x143);
  #undef DPP_MAX
  smax = __int_as_float(__builtin_amdgcn_readlane(__float_as_int(v), 63));
  u64 msk = __ballot(bd == smax);
  int winlane = (int)__ffsll((long long)msk) - 1;
  wbi = __builtin_amdgcn_readlane(bi, winlane);
}

// ---------------- FPS stage 0 (standalone, exact, batch 0) ----------------
// Packed-fp32 dist update (v_pk ops IEEE rn per lane, association preserved,
// contract(off) -> bit-identical to numpy f32). Tie rules = jnp.argmax.
template<int PPT>
__global__ __launch_bounds__(256)
void k_fps4(const float* __restrict__ xs, const float* __restrict__ ys, const float* __restrict__ zs,
            int N, int G, int* __restrict__ fi,
            float* __restrict__ nxs, float* __restrict__ nys, float* __restrict__ nzs){
  constexpr int PH = PPT/2;
  __shared__ float4 sp[4096];
  __shared__ int sfi[2048];
  __shared__ u64 cand[2][4];
  int tid = threadIdx.x;
  const int base = tid * PPT;
  int wv = tid >> 6;
  int lane = tid & 63;
  v2f px[PH], py[PH], pz[PH], dmn[PH];
  #pragma unroll
  for (int j=0;j<PH;j++){
    int n = base + 2*j;
    float2 ax = *(const float2*)(xs+n);
    float2 ay = *(const float2*)(ys+n);
    float2 az = *(const float2*)(zs+n);
    px[j] = (v2f){ax.x, ax.y};
    py[j] = (v2f){ay.x, ay.y};
    pz[j] = (v2f){az.x, az.y};
    sp[n]   = make_float4(ax.x, ay.x, az.x, 0.f);
    sp[n+1] = make_float4(ax.y, ay.y, az.y, 0.f);
    dmn[j] = (v2f){INFINITY, INFINITY};
  }
  if (tid==0){ sfi[0]=0; }
  float lx = xs[0], ly = ys[0], lz = zs[0];
  __syncthreads();
  for (int t=1; t<G; t++){
    float bd = -INFINITY; int bi = base;
    v2f lx2 = (v2f){lx,lx}, ly2 = (v2f){ly,ly}, lz2 = (v2f){lz,lz};
    {
      #pragma clang fp contract(off)
      #pragma unroll
      for (int j=0;j<PH;j++){
        v2f dx = px[j] - lx2;
        v2f dy = py[j] - ly2;
        v2f dz = pz[j] - lz2;
        v2f d2 = (dx*dx + dy*dy) + dz*dz;
        v2f dmo = dmn[j];
        float dm0 = fminf(dmo.x, d2.x);
        float dm1 = fminf(dmo.y, d2.y);
        dmn[j] = (v2f){dm0, dm1};
        bool g0 = dm0 > bd;
        bd = g0 ? dm0 : bd;
        bi = g0 ? (base + 2*j) : bi;
        bool g1 = dm1 > bd;
        bd = g1 ? dm1 : bd;
        bi = g1 ? (base + 2*j + 1) : bi;
      }
    }
    float smax; int wbi;
    wave_argmax(bd, bi, smax, wbi);
    int par = t & 1;
    if (lane == 0) cand[par][wv] = ((u64)__float_as_uint(smax) << 32) | (u32)(~(u32)wbi);
    __syncthreads();
    u64 k0 = cand[par][0], k1 = cand[par][1], k2 = cand[par][2], k3 = cand[par][3];
    u64 ka = k0 > k1 ? k0 : k1;
    u64 kb = k2 > k3 ? k2 : k3;
    u64 km = ka > kb ? ka : kb;
    int w = (int)(~(u32)km);
    if ((u32)w >= (u32)N) w = 0;
    float4 p = sp[w];
    lx = p.x; ly = p.y; lz = p.z;
    if (tid==0){ sfi[t] = w; }
  }
  __syncthreads();
  for (int i = tid; i < G; i += 256) fi[i] = sfi[i];
  for (int i = tid; i < BB*G; i += 256){
    int b = i / G, g = i % G;
    int idx = sfi[g];
    nxs[i] = xs[(size_t)b*N + idx];
    nys[i] = ys[(size_t)b*N + idx];
    nzs[i] = zs[(size_t)b*N + idx];
  }
}

// ---------------- fused kNN (exact radix select) + std partials + embedded next-FPS ----------------
__device__ float blockReduceSum(float v, float* sRed){
  for (int off=32; off; off>>=1) v += __shfl_down(v, off, 64);
  int wid = threadIdx.x >> 6, lane = threadIdx.x & 63;
  __syncthreads();
  if (lane==0) sRed[wid] = v;
  __syncthreads();
  float r = 0;
  if (threadIdx.x == 0){ for (int i=0;i<4;i++) r += sRed[i]; }
  return r;
}

// NF = next-stage point count (== current G); 0 = no embedded FPS.
// Block 0 (when NF>0) runs FPS(s+1) over the batch-0 centers nxs[0..NF),
// writing fi2 + next centers — fully independent of the kNN blocks (read-read
// sharing only), so no inter-block ordering is assumed. Block 0 is dispatched
// first -> overlaps the whole kNN phase.
template<int C, int NF>
__global__ __launch_bounds__(256)
void k_knnstd(const float* __restrict__ x,
              const float* __restrict__ xs, const float* __restrict__ ys, const float* __restrict__ zs,
              const float* __restrict__ nxs, const float* __restrict__ nys, const float* __restrict__ nzs,
              const int* __restrict__ fi, int N, int G,
              int* __restrict__ ki, float* __restrict__ sums,
              int* __restrict__ fi2, float* __restrict__ n2xs,
              float* __restrict__ n2ys, float* __restrict__ n2zs){
  extern __shared__ u32 smk[];
  __shared__ u64 candF[2][4];
  int tid = threadIdx.x;
  if constexpr (NF > 0){
    if (blockIdx.x == 0){
      constexpr int PPT = NF/256;
      constexpr int PH = PPT/2;
      constexpr int G2 = NF/2;
      float4* sp = (float4*)smk;
      int* sfi = ((int*)smk) + NF*4;
      const int base = tid * PPT;
      int wv = tid >> 6, lane = tid & 63;
      v2f px[PH], py[PH], pz[PH], dmn[PH];
      #pragma unroll
      for (int j=0;j<PH;j++){
        int n = base + 2*j;
        float2 ax = *(const float2*)(nxs+n);
        float2 ay = *(const float2*)(nys+n);
        float2 az = *(const float2*)(nzs+n);
        px[j] = (v2f){ax.x, ax.y};
        py[j] = (v2f){ay.x, ay.y};
        pz[j] = (v2f){az.x, az.y};
        sp[n]   = make_float4(ax.x, ay.x, az.x, 0.f);
        sp[n+1] = make_float4(ax.y, ay.y, az.y, 0.f);
        dmn[j] = (v2f){INFINITY, INFINITY};
      }
      if (tid==0){ sfi[0]=0; }
      float lx = nxs[0], ly = nys[0], lz = nzs[0];
      __syncthreads();
      for (int t=1; t<G2; t++){
        float bd = -INFINITY; int bi = base;
        v2f lx2 = (v2f){lx,lx}, ly2 = (v2f){ly,ly}, lz2 = (v2f){lz,lz};
        {
          #pragma clang fp contract(off)
          #pragma unroll
          for (int j=0;j<PH;j++){
            v2f dx = px[j] - lx2;
            v2f dy = py[j] - ly2;
            v2f dz = pz[j] - lz2;
            v2f d2 = (dx*dx + dy*dy) + dz*dz;
            v2f dmo = dmn[j];
            float dm0 = fminf(dmo.x, d2.x);
            float dm1 = fminf(dmo.y, d2.y);
            dmn[j] = (v2f){dm0, dm1};
            bool g0 = dm0 > bd;
            bd = g0 ? dm0 : bd;
            bi = g0 ? (base + 2*j) : bi;
            bool g1 = dm1 > bd;
            bd = g1 ? dm1 : bd;
            bi = g1 ? (base + 2*j + 1) : bi;
          }
        }
        float smax; int wbi;
        wave_argmax(bd, bi, smax, wbi);
        int par = t & 1;
        if (lane == 0) candF[par][wv] = ((u64)__float_as_uint(smax) << 32) | (u32)(~(u32)wbi);
        __syncthreads();
        u64 k0 = candF[par][0], k1 = candF[par][1], k2 = candF[par][2], k3 = candF[par][3];
        u64 ka = k0 > k1 ? k0 : k1;
        u64 kb = k2 > k3 ? k2 : k3;
        u64 km = ka > kb ? ka : kb;
        int w = (int)(~(u32)km);
        if ((u32)w >= (u32)NF) w = 0;
        float4 p = sp[w];
        lx = p.x; ly = p.y; lz = p.z;
        if (tid==0){ sfi[t] = w; }
      }
      __syncthreads();
      for (int i = tid; i < G2; i += 256) fi2[i] = sfi[i];
      for (int i = tid; i < BB*G2; i += 256){
        int b2 = i / G2, g2 = i % G2;
        int idx = sfi[g2];
        n2xs[i] = nxs[(size_t)b2*G + idx];
        n2ys[i] = nys[(size_t)b2*G + idx];
        n2zs[i] = nzs[(size_t)b2*G + idx];
      }
      return;
    }
  }
  u32* keys = smk;           // N
  u32* hist = smk + N;       // 256
  u32* eq   = hist + 256;    // 512
  u32* sc   = eq + 512;      // [0]=prefix [1]=base [2]=outcnt [3]=eqcnt
  u32* wtot = sc + 4;        // 4 wave totals
  __shared__ float sLcx[C];
  __shared__ int sKi[KNB];
  __shared__ int sFi;
  __shared__ float sRed[4];
  int bid = (NF > 0) ? ((int)blockIdx.x - 1) : (int)blockIdx.x;
  int wv = tid >> 6, lane = tid & 63;
  int g = bid % G, b = bid / G;
  if (tid==0){ int f0 = fi[g]; if ((u32)f0 >= (u32)N) f0 = 0; sFi = f0; }
  float cx = nxs[b*G+g], cy = nys[b*G+g], cz = nzs[b*G+g];
  float ss = __fadd_rn(__fadd_rn(__fmul_rn(cx,cx), __fmul_rn(cy,cy)), __fmul_rn(cz,cz));
  for (int n = tid; n < N; n += 256){
    float px = xs[b*N+n], py = ys[b*N+n], pz = zs[b*N+n];
    float nn  = __fadd_rn(__fadd_rn(__fmul_rn(px,px), __fmul_rn(py,py)), __fmul_rn(pz,pz));
    float dot = __fadd_rn(__fadd_rn(__fmul_rn(cx,px), __fmul_rn(cy,py)), __fmul_rn(cz,pz));
    float sq  = __fsub_rn(__fadd_rn(ss, nn), __fmul_rn(2.0f, dot));
    u32 u = __float_as_uint(sq);
    keys[n] = (u & 0x80000000u) ? ~u : (u | 0x80000000u);
  }
  if (tid < 4) sc[tid] = 0;
  __syncthreads();
  for (int c = tid; c < C; c += 256) sLcx[c] = x[(size_t)(b*N + sFi)*C + c];
  u32 prefix = 0, bas = 0;
  for (int pass=0; pass<4; pass++){
    int shift = 24 - 8*pass;
    u32 mask = (pass==0) ? 0u : (0xFFFFFFFFu << (shift+8));
    hist[tid] = 0;
    __syncthreads();
    for (int n = tid; n < N; n += 256){
      u32 k = keys[n];
      if ((k & mask) == (prefix & mask))
        atomicAdd(&hist[(k >> shift) & 255u], 1u);
    }
    __syncthreads();
    u32 h = hist[tid];
    u32 p = h;
    #pragma unroll
    for (int off=1; off<64; off<<=1){
      u32 o = __shfl_up(p, off, 64);
      if (lane >= off) p += o;
    }
    if (lane == 63) wtot[wv] = p;
    __syncthreads();
    u32 ex = p - h;
    for (int w2=0; w2<wv; w2++) ex += wtot[w2];
    if (bas + ex < KNB && bas + ex + h >= KNB){
      sc[0] = prefix | ((u32)tid << shift);
      sc[1] = bas + ex;
    }
    __syncthreads();
    prefix = sc[0]; bas = sc[1];
    __syncthreads();
  }
  u32 T = prefix;
  int needEq = KNB - (int)bas;
  int* out = ki + (size_t)(b*G+g)*KNB;
  for (int n = tid; n < N; n += 256){
    u32 k = keys[n];
    if (k < T){
      u32 p2 = atomicAdd(&sc[2], 1u);
      if (p2 < KNB){ out[p2] = n; sKi[p2] = n; }
    } else if (k == T){
      u32 e = atomicAdd(&sc[3], 1u);
      if (e < 512) eq[e] = (u32)n;
    }
  }
  __syncthreads();
  int m = (int)sc[3]; if (m > 512) m = 512;
  for (int i = tid; i < m; i += 256){
    u32 v = eq[i];
    int r = 0;
    for (int j=0; j<m; j++) r += (eq[j] < v);
    if (r < needEq){
      u32 p2 = atomicAdd(&sc[2], 1u);
      if (p2 < KNB){ out[p2] = (int)v; sKi[p2] = (int)v; }
    }
  }
  __syncthreads();
  if (tid == 0){
    u32 c = sc[2];
    while (c < KNB){ out[c] = 0; sKi[c] = 0; c++; }
  }
  __syncthreads();
  // ---- std partial sums over the selected neighbors ----
  float s1=0, s2=0, s3=0, s4=0;
  constexpr int C2 = C/2;
  for (int u2 = tid; u2 < KNB*C2; u2 += 256){
    int k = u2 / C2; int c = (u2 - k*C2)*2;
    int idx = sKi[k];
    float2 v = *(const float2*)(x + (size_t)(b*N + idx)*C + c);
    float a0 = v.x - sLcx[c];
    float a1 = v.y - sLcx[c+1];
    s1 += a0 + a1; s2 += a0*a0 + a1*a1;
  }
  if (tid < 3){
    for (int k=0;k<KNB;k++){
      int idx = sKi[k];
      float pc = (tid==0 ? xs[b*N+idx] : tid==1 ? ys[b*N+idx] : zs[b*N+idx]);
      float cc = (tid==0 ? cx : tid==1 ? cy : cz);
      float w = pc - cc;
      s3 += w; s4 += w*w;
    }
  }
  float t;
  t = blockReduceSum(s1, sRed); if (tid==0) atomicAdd(&sums[0], t);
  t = blockReduceSum(s2, sRed); if (tid==0) atomicAdd(&sums[1], t);
  t = blockReduceSum(s3, sRed); if (tid==0) atomicAdd(&sums[2], t);
  t = blockReduceSum(s4, sRed); if (tid==0) atomicAdd(&sums[3], t);
}

// ---------------- main feature kernel: w = (feat+pe)*pe, max+mean over K ----------------
template<int C>
__global__ void k_feat(const float* __restrict__ x,
            const float* __restrict__ xs, const float* __restrict__ ys, const float* __restrict__ zs,
            const float* __restrict__ nxs, const float* __restrict__ nys, const float* __restrict__ nzs,
            const int* __restrict__ fi, const int* __restrict__ ki, const float* __restrict__ sums,
            double n1, double n2,
            int N, int G, float* __restrict__ lc){
  constexpr int D = 2*C;
  constexpr int D3 = D/3;
  constexpr int FD = C/3;
  __shared__ float sLcx[C];
  __shared__ float sDx[KNB*3];
  __shared__ int sKi[KNB];
  __shared__ int sFi;
  __shared__ float sC[3];
  __shared__ float sInv2[2];
  int tid = threadIdx.x;
  int g = blockIdx.x % G, b = blockIdx.x / G;
  if (tid==0){ int f0 = fi[g]; if ((u32)f0 >= (u32)N) f0 = 0; sFi = f0; }
  if (tid==0){
    double s1 = sums[0], s2 = sums[1];
    double mean = s1/n1;
    double var = (s2 - s1*mean)/(n1 - 1.0); if (var < 0) var = 0;
    sInv2[0] = (float)(1.0/(sqrt(var) + 1e-5));
    double t1 = sums[2], t2 = sums[3];
    double m2 = t1/n2;
    double v2 = (t2 - t1*m2)/(n2 - 1.0); if (v2 < 0) v2 = 0;
    sInv2[1] = (float)(1.0/(sqrt(v2) + 1e-5));
  }
  if (tid<3) sC[tid] = (tid==0 ? nxs[b*G+g] : tid==1 ? nys[b*G+g] : nzs[b*G+g]);
  if (tid < KNB){ int v = ki[(size_t)(b*G+g)*KNB + tid]; if ((u32)v >= (u32)N) v = 0; sKi[tid] = v; }
  __syncthreads();
  for (int c = tid; c < C; c += blockDim.x) sLcx[c] = x[(size_t)(b*N + sFi)*C + c];
  for (int t = tid; t < KNB*3; t += blockDim.x){
    int k = t/3, c = t%3;
    int idx = sKi[k];
    float pc = (c==0 ? xs[b*N+idx] : c==1 ? ys[b*N+idx] : zs[b*N+idx]);
    sDx[t] = (pc - sC[c]) * sInv2[1];
  }
  __syncthreads();
  int p = tid;
  if (p >= C) return;
  int d0 = 2*p;
  int c = d0 / D3;
  int f = (d0 - c*D3) >> 1;
  float rcp = __powf(1000.0f, -(float)f / (float)FD);
  bool low = (d0 < C);
  float invdx = sInv2[0];
  float fh0 = 0.f, fh1 = 0.f;
  if (!low){ fh0 = sLcx[d0-C]; fh1 = sLcx[d0+1-C]; }
  float l0 = low ? sLcx[d0] : 0.f, l1 = low ? sLcx[d0+1] : 0.f;
  float mx0=-INFINITY, mx1=-INFINITY, sm0=0.f, sm1=0.f;
  for (int k=0;k<KNB;k++){
    float a = (100.0f * sDx[k*3+c]) * rcp;
    float sn, cs; __sincosf(a, &sn, &cs);
    float f0, f1;
    if (low){
      float2 v = *(const float2*)(x + (size_t)(b*N + sKi[k])*C + d0);
      f0 = (v.x - l0) * invdx;
      f1 = (v.y - l1) * invdx;
    } else { f0 = fh0; f1 = fh1; }
    float w0 = (f0 + sn)*sn;
    float w1 = (f1 + cs)*cs;
    mx0 = fmaxf(mx0, w0); sm0 += w0;
    mx1 = fmaxf(mx1, w1); sm1 += w1;
  }
  float* o = lc + (size_t)(b*G+g)*D + d0;
  o[0] = mx0 + sm0/90.0f;
  o[1] = mx1 + sm1/90.0f;
}

// ---------------- BatchNorm: parallel partial stats ----------------
__global__ __launch_bounds__(256)
void k_bnpart(const float* __restrict__ lc, int D, int M,
              double* __restrict__ PS, double* __restrict__ PQ){
  __shared__ double sS[4][64], sQ[4][64];
  int lane = threadIdx.x & 63, row = threadIdx.x >> 6;
  int tile = blockIdx.x, stripe = blockIdx.y;
  int d = tile*64 + lane;
  int span = M / NSTRIPE;
  int i0 = stripe * span;
  double s=0, q=0;
  if (d < D){
    for (int i=i0+row; i<i0+span; i+=4){
      float v = lc[(size_t)i*D + d];
      s += v; q += (double)v*v;
    }
  }
  sS[row][lane]=s; sQ[row][lane]=q;
  __syncthreads();
  if (row==0 && d < D){
    PS[(size_t)stripe*MAXD + d] = sS[0][lane]+sS[1][lane]+sS[2][lane]+sS[3][lane];
    PQ[(size_t)stripe*MAXD + d] = sQ[0][lane]+sQ[1][lane]+sQ[2][lane]+sQ[3][lane];
  }
}

__global__ void k_bnfin(const double* __restrict__ PS, const double* __restrict__ PQ,
                        const float* __restrict__ gamma, const float* __restrict__ beta,
                        int D, int M, float* __restrict__ A, float* __restrict__ Bb){
  int d = blockIdx.x*64 + threadIdx.x;
  if (d >= D) return;
  double ts=0, tq=0;
  for (int s=0; s<NSTRIPE; s++){ ts += PS[(size_t)s*MAXD + d]; tq += PQ[(size_t)s*MAXD + d]; }
  double mean = ts / M;
  double var = tq / M - mean*mean; if (var < 0) var = 0;
  float rstd = (float)(1.0/sqrt(var + 1e-5));
  float gm = gamma[d], bt = beta[d];
  A[d] = gm*rstd;
  Bb[d] = bt - (float)mean*gm*rstd;
}

// in-place BN + GELU — large coalesced grid
__global__ void k_apply(float* __restrict__ lc, const float* __restrict__ A,
                        const float* __restrict__ Bb, int D, int total){
  int i = blockIdx.x*blockDim.x + threadIdx.x;
  if (i >= total) return;
  int d = i % D;
  float v = lc[i]*A[d] + Bb[d];
  lc[i] = 0.5f * v * (1.0f + erff(v * 0.70710678118654752f));
}

__global__ void k_out(const float* __restrict__ feat, float* __restrict__ out){
  int i = blockIdx.x*blockDim.x + threadIdx.x;
  if (i >= BB*1152) return;
  int b = i / 1152, d = i % 1152;
  const float* base = feat + (size_t)b*256*1152 + d;
  float mx = -INFINITY, sm = 0.f;
  for (int g=0; g<256; g++){
    float v = base[(size_t)g*1152];
    mx = fmaxf(mx, v); sm += v;
  }
  out[i] = mx + sm/256.0f;
}

// ---------------- launch ----------------
extern "C" void kernel_launch(void* const* d_in, const int* in_sizes, int n_in,
                              void* d_out, int out_size, void* d_ws, size_t ws_size,
                              hipStream_t stream) {
  const float* xyz = (const float*)d_in[0];
  const float* xin = (const float*)d_in[1];
  float* ws = (float*)d_ws;
  size_t off = 0;
  const size_t PS_ = (size_t)BB*NP0;
  const size_t XS = (size_t)BB*NP0*CC0;
  float* T0[3]; float* T1[3]; float* T2[3];
  for (int i=0;i<3;i++){ T0[i] = ws + off; off += PS_; }
  for (int i=0;i<3;i++){ T1[i] = ws + off; off += PS_; }
  for (int i=0;i<3;i++){ T2[i] = ws + off; off += PS_; }
  float* xA = ws + off; off += XS;
  float* xB = ws + off; off += XS;
  int*   fiA = (int*)(ws + off); off += 2048;
  int*   fiB = (int*)(ws + off); off += 2048;
  int*   ki = (int*)(ws + off); off += (size_t)BB*2048*KNB;
  float* sums = ws + off; off += 16;
  float* Abn  = ws + off; off += 1152;
  float* Bbn  = ws + off; off += 1152;
  off = (off + 1) & ~(size_t)1;
  double* PSb = (double*)(ws + off); off += (size_t)NSTRIPE*MAXD*2;
  double* PQb = (double*)(ws + off); off += (size_t)NSTRIPE*MAXD*2;

  k_init<<<(BB*NP0*36+255)/256, 256, 0, stream>>>(xyz, xin, T0[0], T0[1], T0[2], xA, sums);
  // stage-0 FPS: points T0 -> fiA + centers T1
  k_fps4<16><<<1, 256, 0, stream>>>(T0[0],T0[1],T0[2], NP0, NP0/2, fiA, T1[0],T1[1],T1[2]);

  float **P = T0, **Cn = T1, **Nx = T2;  // points, centers, next-centers
  int *fiC = fiA, *fiN = fiB;
  float *xc = xA, *lc = xB;
  for (int s=0; s<4; s++){
    int N = NP0 >> s, G = N >> 1, C = CC0 << s, D = 2*C;
    float* ssum = sums + 4*s;
    size_t knn_need = (size_t)(N + 256 + 512 + 8 + 8)*4;
    if (s==0){
      size_t lds = knn_need; size_t fps_need = (size_t)2048*16 + 1024*4;
      if (fps_need > lds) lds = fps_need;
      k_knnstd<72,2048><<<BB*G+1, 256, lds, stream>>>(xc, P[0],P[1],P[2], Cn[0],Cn[1],Cn[2],
          fiC, N, G, ki, ssum, fiN, Nx[0],Nx[1],Nx[2]);
    } else if (s==1){
      size_t lds = knn_need; size_t fps_need = (size_t)1024*16 + 512*4;
      if (fps_need > lds) lds = fps_need;
      k_knnstd<144,1024><<<BB*G+1, 256, lds, stream>>>(xc, P[0],P[1],P[2], Cn[0],Cn[1],Cn[2],
          fiC, N, G, ki, ssum, fiN, Nx[0],Nx[1],Nx[2]);
    } else if (s==2){
      size_t lds = knn_need; size_t fps_need = (size_t)512*16 + 256*4;
      if (fps_need > lds) lds = fps_need;
      k_knnstd<288,512><<<BB*G+1, 256, lds, stream>>>(xc, P[0],P[1],P[2], Cn[0],Cn[1],Cn[2],
          fiC, N, G, ki, ssum, fiN, Nx[0],Nx[1],Nx[2]);
    } else {
      k_knnstd<576,0><<<BB*G, 256, knn_need, stream>>>(xc, P[0],P[1],P[2], Cn[0],Cn[1],Cn[2],
          fiC, N, G, ki, ssum, nullptr, nullptr, nullptr, nullptr);
    }
    double n1 = (double)BB*G*KNB*C, n2 = (double)BB*G*KNB*3;
    int Tp = ((C + 63)/64)*64;
    if (s==0)      k_feat<72 ><<<BB*G, Tp, 0, stream>>>(xc, P[0],P[1],P[2], Cn[0],Cn[1],Cn[2], fiC, ki, ssum, n1, n2, N, G, lc);
    else if (s==1) k_feat<144><<<BB*G, Tp, 0, stream>>>(xc, P[0],P[1],P[2], Cn[0],Cn[1],Cn[2], fiC, ki, ssum, n1, n2, N, G, lc);
    else if (s==2) k_feat<288><<<BB*G, Tp, 0, stream>>>(xc, P[0],P[1],P[2], Cn[0],Cn[1],Cn[2], fiC, ki, ssum, n1, n2, N, G, lc);
    else           k_feat<576><<<BB*G, Tp, 0, stream>>>(xc, P[0],P[1],P[2], Cn[0],Cn[1],Cn[2], fiC, ki, ssum, n1, n2, N, G, lc);
    int M = BB*G;
    dim3 bng((D + 63)/64, NSTRIPE);
    k_bnpart<<<bng, 256, 0, stream>>>(lc, D, M, PSb, PQb);
    k_bnfin<<<(D + 63)/64, 64, 0, stream>>>(PSb, PQb, (const float*)d_in[2+2*s],
                                            (const float*)d_in[3+2*s], D, M, Abn, Bbn);
    int total = M*D;
    k_apply<<<(total+255)/256, 256, 0, stream>>>(lc, Abn, Bbn, D, total);
    // rotate: points <- centers, centers <- next-centers, next <- old points
    float** t = P; P = Cn; Cn = Nx; Nx = t;
    int* ti = fiC; fiC = fiN; fiN = ti;
    float* tf = xc; xc = lc; lc = tf;
  }
  k_out<<<(BB*1152+255)/256, 256, 0, stream>>>(xc, (float*)d_out);
}